// Round 12
// baseline (708.983 us; speedup 1.0000x reference)
//
#include <hip/hip_runtime.h>
#include <math.h>

#define DEV __device__ __forceinline__

typedef _Float16 f16x8 __attribute__((ext_vector_type(8)));
typedef _Float16 f16x4 __attribute__((ext_vector_type(4)));
typedef float    f32x4 __attribute__((ext_vector_type(4)));

DEV float sigmoidf_(float x){ return 1.0f/(1.0f + expf(-x)); }

DEV float wred64(float x){
    #pragma unroll
    for (int off=32; off; off>>=1) x += __shfl_xor(x, off);
    return x;
}

#define MFMA16(a,b,c) __builtin_amdgcn_mfma_f32_16x16x32_f16(a,b,c,0,0,0)

// ---------------- pack helper: frag layout, f16 hi/lo ------------------
DEV void packone(const float* __restrict__ src, int N, int NfrTot, int nfOff,
                 _Float16* __restrict__ Dh, _Float16* __restrict__ Dl, int o){
    int j = o&7, l16 = (o>>3)&15, kg = (o>>7)&3;
    int rest = o>>9;
    int nfl = rest % (N>>4), kt = rest / (N>>4);
    int k = kt*32 + kg*8 + j, n = nfl*16 + l16;
    float x = src[(size_t)k*N + n];
    _Float16 h = (_Float16)x;
    size_t d = ((size_t)kt*NfrTot + nfOff + nfl)*512 + kg*128 + l16*8 + j;
    Dh[d] = h; Dl[d] = (_Float16)(x - (float)h);
}

// ---------------- merged prep: faW, Bh/Bl, Wh/Wl, PKfv, PKxv -----------
__global__ __launch_bounds__(256) void k_prep(
    const float* __restrict__ fa_w1, const float* __restrict__ fa_w2, float* __restrict__ faW,
    const float* __restrict__ fv_w1, const float* __restrict__ fv_w2,
    const float* __restrict__ av_vw, _Float16* __restrict__ Bh, _Float16* __restrict__ Bl,
    const float* __restrict__ v2w, _Float16* __restrict__ Wh, _Float16* __restrict__ Wl,
    const float* __restrict__ lv_wih,
    _Float16* __restrict__ PKfv_h, _Float16* __restrict__ PKfv_l,
    _Float16* __restrict__ PKxv_h, _Float16* __restrict__ PKxv_l)
{
    int bid = blockIdx.x, t = threadIdx.x;
    if (bid < 64){
        int idx = bid*256+t; int m = idx>>7, n = idx&127;
        float acc=0.f;
        for (int k=0;k<256;k++) acc += fa_w1[m*256+k]*fa_w2[k*128+n];
        faW[idx]=acc;
    } else if (bid < 1088){
        int o = (bid-64)*256+t;
        int j = o & 7, l16 = (o>>3)&15, kg = (o>>7)&3, nf = (o>>9)&31, kt = o>>14;
        int k = kt*32 + kg*8 + j, n = nf*16 + l16;
        float x = av_vw[(size_t)k*512 + n];
        _Float16 h = (_Float16)x;
        Bh[o] = h; Bl[o] = (_Float16)(x - (float)h);
    } else if (bid < 1216){
        int o = (bid-1088)*256+t;
        int j = o & 7, l16 = (o>>3)&15, kg = (o>>7)&3, qf = (o>>9)&3, kbg = o>>11;
        int k = kbg*32 + kg*8 + j, q = qf*16 + l16;
        float x = (q < 49) ? v2w[(size_t)k*49 + q] : 0.f;
        _Float16 h = (_Float16)x;
        Wh[o] = h; Wl[o] = (_Float16)(x - (float)h);
    } else if (bid < 1472){
        int o = (bid-1216)*256+t;
        int j=o&7, l16=(o>>3)&15, kg=(o>>7)&3; int rest=o>>9;
        int nfl = rest&7, kt = rest>>3;
        int k = kt*32+kg*8+j, n = nfl*16+l16;
        float acc=0.f;
        for (int kk=0;kk<256;kk++) acc += fv_w1[k*256+kk]*fv_w2[kk*128+n];
        _Float16 h=(_Float16)acc;
        size_t d = ((size_t)kt*8 + nfl)*512 + kg*128 + l16*8 + j;
        PKfv_h[d]=h; PKfv_l[d]=(_Float16)(acc-(float)h);
    } else {
        int seg = (bid-1472)>>8;
        int o = ((bid-1472)&255)*256+t;
        packone(lv_wih + (size_t)seg*65536, 512, 64, seg*32, PKxv_h, PKxv_l, o);
    }
}

// ---------------- fused fa + a_h + ga + xpA, 8 bt per block ------------
__global__ __launch_bounds__(256) void k_faga2(
    const float* __restrict__ audio, const float* __restrict__ faW,
    const float* __restrict__ av_aw, const float* __restrict__ av_ab,
    const float* __restrict__ av_gw,
    const float* __restrict__ la_wih, const float* __restrict__ la_b,
    float* __restrict__ gGA, float* __restrict__ xpA)
{
    int b0 = blockIdx.x*8; int t = threadIdx.x;
    __shared__ float sau[8][128], sfa[8][128], sah[8][512];
    for (int i=t;i<1024;i+=256){ int bt=i>>7,k=i&127; sau[bt][k]=audio[(size_t)(b0+bt)*128+k]; }
    __syncthreads();
    for (int u=0;u<4;u++){
        int i=t+u*256, bt=i>>7, n=i&127;
        float acc=0.f;
        for (int k4=0;k4<32;k4++){
            float4 x4=*(const float4*)&sau[bt][k4*4];
            acc+=x4.x*faW[(k4*4)*128+n]+x4.y*faW[(k4*4+1)*128+n]
                +x4.z*faW[(k4*4+2)*128+n]+x4.w*faW[(k4*4+3)*128+n];
        }
        sfa[bt][n]=acc;
    }
    __syncthreads();
    for (int u=0;u<2;u++){
        int n=t+u*256;
        float bv=av_ab[n];
        float acc[8]={bv,bv,bv,bv,bv,bv,bv,bv};
        for (int k4=0;k4<32;k4++){
            float w0=av_aw[(k4*4)*512+n], w1=av_aw[(k4*4+1)*512+n],
                  w2=av_aw[(k4*4+2)*512+n], w3=av_aw[(k4*4+3)*512+n];
            #pragma unroll
            for (int bt=0;bt<8;bt++){
                float4 x4=*(const float4*)&sfa[bt][k4*4];
                acc[bt]+=x4.x*w0+x4.y*w1+x4.z*w2+x4.w*w3;
            }
        }
        #pragma unroll
        for (int bt=0;bt<8;bt++) sah[bt][n]=fmaxf(acc[bt],0.f);
    }
    __syncthreads();
    for (int hh=0;hh<2;hh++){
        if (t<196){
            int bt=hh*4 + t/49, q=t%49;
            float acc=0.f;
            for (int k=0;k<512;k++) acc+=sah[bt][k]*av_gw[k*49+q];
            gGA[(size_t)(b0+bt)*49+q]=acc;
        }
    }
    for (int u=0;u<4;u++){
        int n = t + u*256;
        int dir = n >> 9, g = n & 511;
        const float* W = la_wih + (size_t)dir*65536;
        float bvv = la_b[dir*512 + g];
        float acc[8] = {bvv,bvv,bvv,bvv,bvv,bvv,bvv,bvv};
        for (int k4=0;k4<32;k4++){
            float w0=W[(k4*4+0)*512+g], w1=W[(k4*4+1)*512+g],
                  w2=W[(k4*4+2)*512+g], w3=W[(k4*4+3)*512+g];
            #pragma unroll
            for (int bt=0;bt<8;bt++){
                float4 x4=*(const float4*)&sfa[bt][k4*4];
                acc[bt]+=x4.x*w0+x4.y*w1+x4.z*w2+x4.w*w3;
            }
        }
        #pragma unroll
        for (int bt=0;bt<8;bt++)
            xpA[((size_t)(b0+bt))*1024 + n] = acc[bt];
    }
}

// ---------------- fully fused AVGA: phase-batched staging --------------
DEV void cvt4_(float4 v, f16x4& hv, f16x4& lv){
    hv[0]=(_Float16)v.x; lv[0]=(_Float16)(v.x-(float)hv[0]);
    hv[1]=(_Float16)v.y; lv[1]=(_Float16)(v.y-(float)hv[1]);
    hv[2]=(_Float16)v.z; lv[2]=(_Float16)(v.z-(float)hv[2]);
    hv[3]=(_Float16)v.w; lv[3]=(_Float16)(v.w-(float)hv[3]);
}

__global__ __launch_bounds__(256,2) void k_avga_fused(
    const float* __restrict__ video,
    const _Float16* __restrict__ Bh, const _Float16* __restrict__ Bl,
    const float* __restrict__ bias,
    const _Float16* __restrict__ Wh, const _Float16* __restrict__ Wl,
    const float* __restrict__ gGA, const float* __restrict__ hw,
    float* __restrict__ vT)
{
    __shared__ __align__(16) char smem[67072];
    // main loop: A-frag bufs for 8 kt at [0,65536), 8KB each (hi 4KB | lo 4KB)
    // epilogue:  vh per wave at w*8192 in [0,32768)
    // reduce:    partials at w*16384 in [0,65536); szp@65536, salpha@66560
    int bt = blockIdx.x;
    int t = threadIdx.x;
    int lane = t & 63, w = t >> 6;
    int l16 = lane & 15, lq = lane >> 4;
    int lb = lane * 16;

    // staging coords (proven pattern): thread t covers rows am, am+32, 4 k
    int am = t >> 3, ak = (t & 7) * 4;
    int aoff1 = ((am>>4)*4 + (ak>>3))*256 + (am&15)*16 + (ak&7)*2;
    int am2 = am + 32;
    int aoff2 = ((am2>>4)*4 + (ak>>3))*256 + (am2&15)*16 + (ak&7)*2;
    size_t r1 = (size_t)bt*49 + am;  if (r1 > 125439) r1 = 125439;
    size_t r2 = (size_t)bt*49 + am2; if (r2 > 125439) r2 = 125439;
    const float* Arow1 = video + r1*512 + ak;
    const float* Arow2 = video + r2*512 + ak;

    const f32x4 vzero = {0.f,0.f,0.f,0.f};
    f32x4 acc[4][8];
    #pragma unroll
    for (int p=0;p<4;p++)
        #pragma unroll
        for (int q=0;q<8;q++) acc[p][q] = vzero;

    for (int ph = 0; ph < 2; ++ph){
        // ---- phase pack: 8 kt-tiles (k range ph*256 .. +256) ----
        for (int kl = 0; kl < 8; ++kl){
            int ko = ph*256 + kl*32;
            float4 a0 = *(const float4*)(Arow1 + ko);
            float4 a1 = *(const float4*)(Arow2 + ko);
            char* h = &smem[kl*8192];
            f16x4 hv, lv;
            cvt4_(a0, hv, lv);
            *(f16x4*)(h + aoff1) = hv; *(f16x4*)(h + 4096 + aoff1) = lv;
            cvt4_(a1, hv, lv);
            *(f16x4*)(h + aoff2) = hv; *(f16x4*)(h + 4096 + aoff2) = lv;
        }
        __syncthreads();
        // ---- 8 kt of pure MFMA, no syncs ----
        for (int kl = 0; kl < 8; ++kl){
            int kt = ph*8 + kl;
            const char* aB = &smem[kl*8192];
            f16x8 ah[4], al[4];
            #pragma unroll
            for (int p=0;p<4;p++){
                ah[p] = *(const f16x8*)(aB + p*1024 + lb);
                al[p] = *(const f16x8*)(aB + 4096 + p*1024 + lb);
            }
            #pragma unroll
            for (int q=0;q<8;q++){
                size_t bo = (size_t)kt*16384 + (size_t)(w*8 + q)*512 + lane*8;
                f16x8 bh  = *(const f16x8*)(Bh + bo);
                f16x8 bl2 = *(const f16x8*)(Bl + bo);
                #pragma unroll
                for (int p=0;p<4;p++){
                    acc[p][q] = MFMA16(ah[p], bh,  acc[p][q]);
                    acc[p][q] = MFMA16(ah[p], bl2, acc[p][q]);
                    acc[p][q] = MFMA16(al[p], bh,  acc[p][q]);
                }
            }
        }
        __syncthreads();   // LDS reuse boundary (next pack / epilogue)
    }

    // ---- epilogue: per-wave VH (bias+relu, f16 hi/lo) + content MFMA --
    float bv[8];
    #pragma unroll
    for (int q=0;q<8;q++) bv[q] = bias[w*128 + q*16 + l16];

    char* vh = &smem[w*8192];
    f32x4 cacc[4][4];
    #pragma unroll
    for (int p=0;p<4;p++)
        #pragma unroll
        for (int qf=0;qf<4;qf++) cacc[p][qf] = vzero;

    #pragma unroll
    for (int c=0;c<4;c++){
        #pragma unroll
        for (int p=0;p<4;p++)
            #pragma unroll
            for (int qq=0;qq<2;qq++){
                int q = c*2 + qq;
                int offbase = p*1024 + (qq*2 + (l16>>3))*256 + (l16&7)*2;
                #pragma unroll
                for (int r=0;r<4;r++){
                    float x = fmaxf(acc[p][q][r] + bv[q], 0.f);
                    _Float16 hh = (_Float16)x;
                    _Float16 ll = (_Float16)(x - (float)hh);
                    int off = offbase + (lq*4 + r)*16;
                    *(_Float16*)(vh + off)        = hh;
                    *(_Float16*)(vh + 4096 + off) = ll;
                }
            }
        int kbg = w*4 + c;
        f16x8 vhh[4], vhl[4];
        #pragma unroll
        for (int p=0;p<4;p++){
            vhh[p] = *(const f16x8*)(vh + p*1024 + lb);
            vhl[p] = *(const f16x8*)(vh + 4096 + p*1024 + lb);
        }
        #pragma unroll
        for (int qf=0;qf<4;qf++){
            size_t wo = (size_t)kbg*2048 + qf*512 + lane*8;
            f16x8 wh = *(const f16x8*)(Wh + wo);
            f16x8 wl = *(const f16x8*)(Wl + wo);
            #pragma unroll
            for (int p=0;p<4;p++){
                cacc[p][qf] = MFMA16(vhh[p], wh, cacc[p][qf]);
                cacc[p][qf] = MFMA16(vhh[p], wl, cacc[p][qf]);
                cacc[p][qf] = MFMA16(vhl[p], wh, cacc[p][qf]);
            }
        }
    }

    // ---- cross-wave content reduce (4-buffer parallel) ----
    __syncthreads();
    float* pw = (float*)&smem[w*16384];
    #pragma unroll
    for (int p=0;p<4;p++)
        #pragma unroll
        for (int qf=0;qf<4;qf++)
            #pragma unroll
            for (int r=0;r<4;r++)
                pw[(p*16 + lq*4 + r)*64 + qf*16 + l16] = cacc[p][qf][r];
    __syncthreads();
    float* cb = (float*)&smem[0];
    for (int i=t; i<4096; i+=256)
        cb[i] = cb[i] + cb[4096+i] + cb[8192+i] + cb[12288+i];
    __syncthreads();

    // ---- z, softmax, weighted sum ----
    float* szp    = (float*)&smem[65536];
    float* salpha = (float*)&smem[66560];
    if (t < 196){
        int p = t >> 2, ds = t & 3;
        float ga = gGA[(size_t)bt*49 + p];
        float part = 0.f;
        for (int q = ds*13; q < ds*13+13 && q < 49; q++)
            part += tanhf(cb[p*64 + q] + ga) * hw[q];
        szp[t] = part;
    }
    __syncthreads();
    if (t < 64){
        float z = (t<49) ? (szp[t*4]+szp[t*4+1]+szp[t*4+2]+szp[t*4+3]) : -1e30f;
        float m = z;
        #pragma unroll
        for (int off=32; off; off>>=1) m = fmaxf(m, __shfl_xor(m, off));
        float e = (t<49)? expf(z - m) : 0.f;
        float s = e;
        #pragma unroll
        for (int off=32; off; off>>=1) s += __shfl_xor(s, off);
        salpha[t] = e / s;
    }
    __syncthreads();
    const float* vb = video + (size_t)bt*49*512;
    #pragma unroll
    for (int u=0;u<2;u++){
        int d = t + u*256;
        float a0 = 0.f;
        for (int p=0;p<49;p++) a0 += salpha[p] * vb[(size_t)p*512 + d];
        vT[(size_t)bt*512 + d] = a0;
    }
}

// ---------------- fused vfea + xpV GEMM (two-phase, MFMA) --------------
__global__ __launch_bounds__(256) void k_gemm2(
    const float* __restrict__ vT,
    const _Float16* __restrict__ Fh, const _Float16* __restrict__ Fl,
    const _Float16* __restrict__ Xh, const _Float16* __restrict__ Xl,
    const float* __restrict__ lv_b,
    float* __restrict__ xpV)
{
    __shared__ __align__(16) char sA[2][4096];
    __shared__ float sV[32][132];
    int t = threadIdx.x, lane = t&63, w = t>>6;
    int l16 = lane&15, lq = lane>>4, lb = lane*16;
    int row0 = blockIdx.x * 32;

    int am = t>>3, ak = (t&7)*4;
    int aoff = ((am>>4)*4 + (ak>>3))*256 + (am&15)*16 + (ak&7)*2;
    const float* Arow = vT + (size_t)(row0+am)*512 + ak;

    const f32x4 vzero = {0.f,0.f,0.f,0.f};
    f32x4 acc1[2][2];
    #pragma unroll
    for (int p=0;p<2;p++)
        #pragma unroll
        for (int q=0;q<2;q++) acc1[p][q] = vzero;

    float4 pa = *(const float4*)(Arow);
    {
        f16x4 hv, lv;
        char* h = &sA[0][0];
        cvt4_(pa, hv, lv);
        *(f16x4*)(h + aoff) = hv; *(f16x4*)(h + 2048 + aoff) = lv;
    }
    __syncthreads();
    for (int kt = 0; kt < 16; ++kt){
        int cur = kt & 1;
        bool more = (kt < 15);
        if (more) pa = *(const float4*)(Arow + (kt+1)*32);
        const char* aB = &sA[cur][0];
        f16x8 ah[2], al[2];
        #pragma unroll
        for (int p=0;p<2;p++){
            ah[p] = *(const f16x8*)(aB + p*1024 + lb);
            al[p] = *(const f16x8*)(aB + 2048 + p*1024 + lb);
        }
        #pragma unroll
        for (int q=0;q<2;q++){
            size_t bo = ((size_t)kt*8 + w*2 + q)*512 + lane*8;
            f16x8 bh  = *(const f16x8*)(Fh + bo);
            f16x8 bl2 = *(const f16x8*)(Fl + bo);
            #pragma unroll
            for (int p=0;p<2;p++){
                acc1[p][q] = MFMA16(ah[p], bh,  acc1[p][q]);
                acc1[p][q] = MFMA16(ah[p], bl2, acc1[p][q]);
                acc1[p][q] = MFMA16(al[p], bh,  acc1[p][q]);
            }
        }
        if (more){
            char* h = &sA[cur^1][0];
            f16x4 hv, lv;
            cvt4_(pa, hv, lv);
            *(f16x4*)(h + aoff) = hv; *(f16x4*)(h + 2048 + aoff) = lv;
        }
        __syncthreads();
    }
    #pragma unroll
    for (int q=0;q<2;q++){
        int n = (w*2+q)*16 + l16;
        #pragma unroll
        for (int p=0;p<2;p++)
            #pragma unroll
            for (int r=0;r<4;r++)
                sV[p*16 + lq*4 + r][n] = acc1[p][q][r];
    }
    __syncthreads();

    int nf0 = blockIdx.y*16 + w*4;
    f32x4 acc2[2][4];
    #pragma unroll
    for (int p=0;p<2;p++)
        #pragma unroll
        for (int q=0;q<4;q++) acc2[p][q] = vzero;

    pa = *(const float4*)&sV[am][ak];
    {
        f16x4 hv, lv;
        char* h = &sA[0][0];
        cvt4_(pa, hv, lv);
        *(f16x4*)(h + aoff) = hv; *(f16x4*)(h + 2048 + aoff) = lv;
    }
    __syncthreads();
    for (int kt = 0; kt < 4; ++kt){
        int cur = kt & 1;
        bool more = (kt < 3);
        if (more) pa = *(const float4*)&sV[am][(kt+1)*32 + ak];
        const char* aB = &sA[cur][0];
        f16x8 ah[2], al[2];
        #pragma unroll
        for (int p=0;p<2;p++){
            ah[p] = *(const f16x8*)(aB + p*1024 + lb);
            al[p] = *(const f16x8*)(aB + 2048 + p*1024 + lb);
        }
        #pragma unroll
        for (int q=0;q<4;q++){
            size_t bo = ((size_t)kt*64 + nf0 + q)*512 + lane*8;
            f16x8 bh  = *(const f16x8*)(Xh + bo);
            f16x8 bl2 = *(const f16x8*)(Xl + bo);
            #pragma unroll
            for (int p=0;p<2;p++){
                acc2[p][q] = MFMA16(ah[p], bh,  acc2[p][q]);
                acc2[p][q] = MFMA16(ah[p], bl2, acc2[p][q]);
                acc2[p][q] = MFMA16(al[p], bh,  acc2[p][q]);
            }
        }
        if (more){
            char* h = &sA[cur^1][0];
            f16x4 hv, lv;
            cvt4_(pa, hv, lv);
            *(f16x4*)(h + aoff) = hv; *(f16x4*)(h + 2048 + aoff) = lv;
        }
        __syncthreads();
    }
    #pragma unroll
    for (int q=0;q<4;q++){
        int n = (nf0+q)*16 + l16;
        float bv = lv_b[n];
        #pragma unroll
        for (int p=0;p<2;p++){
            #pragma unroll
            for (int r=0;r<4;r++)
                xpV[(size_t)(row0 + p*16 + lq*4 + r)*1024 + n] = acc2[p][q][r] + bv;
        }
    }
}

// ---------------- persistent bidirectional LSTMs (256 blocks) ----------
__global__ __launch_bounds__(256) void k_lstm(
    const float* __restrict__ xpA, const float* __restrict__ xpV,
    const float* __restrict__ la_whh, const float* __restrict__ lv_whh,
    float* __restrict__ lstm_a, float* __restrict__ lstm_v)
{
    int blk = blockIdx.x;
    int c = blk >> 6;
    int chunk = blk & 63;
    int t = threadIdx.x;
    int j  = t & 127;
    int bh = t >> 7;
    const float* whh = ((c<2)? la_whh : lv_whh) + (size_t)(c&1)*128*512;
    const float* xpm = (c<2)? xpA : xpV;
    float* outp = (c<2)? lstm_a : lstm_v;
    int dir = c & 1;

    __shared__ float hbuf[4][128];
    float cc[2] = {0.f,0.f};
    for (int i=t;i<512;i+=256) ((float*)hbuf)[i] = 0.f;
    __syncthreads();

    for (int s=0; s<10; s++){
        int tt = dir ? (9-s) : s;
        float gi[2], gf[2], gg[2], go[2];
        #pragma unroll
        for (int b=0;b<2;b++){
            int gb = chunk*4 + bh*2 + b;
            const float* xrow = xpm + ((size_t)gb*10 + tt)*1024 + dir*512;
            gi[b]=xrow[j]; gf[b]=xrow[128+j]; gg[b]=xrow[256+j]; go[b]=xrow[384+j];
        }
        #pragma unroll 4
        for (int k=0;k<128;k++){
            float wi = whh[k*512 + j];
            float wf = whh[k*512 + 128 + j];
            float wg = whh[k*512 + 256 + j];
            float wo = whh[k*512 + 384 + j];
            #pragma unroll
            for (int b=0;b<2;b++){
                float hk = hbuf[bh*2+b][k];
                gi[b] += hk*wi; gf[b] += hk*wf; gg[b] += hk*wg; go[b] += hk*wo;
            }
        }
        __syncthreads();
        #pragma unroll
        for (int b=0;b<2;b++){
            float i_ = sigmoidf_(gi[b]);
            float f_ = sigmoidf_(gf[b]);
            float g_ = tanhf(gg[b]);
            float o_ = sigmoidf_(go[b]);
            cc[b] = f_*cc[b] + i_*g_;
            float h_ = o_*tanhf(cc[b]);
            hbuf[bh*2+b][j] = h_;
            int gb = chunk*4 + bh*2 + b;
            outp[((size_t)gb*10 + tt)*256 + dir*128 + j] = h_;
        }
        __syncthreads();
    }
}

// ---------------- per-sample tail: branches+att+psp+fc+LN+MLP ----------
__global__ __launch_bounds__(256) void k_tail(
    const float* __restrict__ lstm_a, const float* __restrict__ lstm_v,
    const float* __restrict__ vL1, const float* __restrict__ vL2,
    const float* __restrict__ aL1, const float* __restrict__ aL2,
    const float* __restrict__ vfc, const float* __restrict__ afc,
    const float* __restrict__ thrp,
    const float* __restrict__ ln_g, const float* __restrict__ ln_b,
    const float* __restrict__ L1w, const float* __restrict__ L2w,
    float* __restrict__ dout)
{
    int b = blockIdx.x, t = threadIdx.x;
    int lane = t & 63, w = t >> 6;
    __shared__ float sla[10][256], slv[10][256];
    __shared__ float sb1v[10][256], sb2v[10][256], sb1a[10][256], sb2a[10][256];
    __shared__ float sfu[10][256];
    __shared__ float s64[10][64];
    __shared__ float satt[100], s_v2a[100], s_a2v[100];
    __shared__ float sredp[160];
    __shared__ float scos[120];

    size_t base = (size_t)b*2560;
    for (int i=t;i<2560;i+=256){
        ((float*)sla)[i] = lstm_a[base+i];
        ((float*)slv)[i] = lstm_v[base+i];
    }
    __syncthreads();

    {
        float a1[10], a2[10];
        #pragma unroll
        for (int r=0;r<10;r++){ a1[r]=0.f; a2[r]=0.f; }
        #pragma unroll 4
        for (int k=0;k<256;k++){
            float w1 = vL1[k*256+t], w2 = vL2[k*256+t];
            #pragma unroll
            for (int r=0;r<10;r++){ float x=slv[r][k]; a1[r]+=x*w1; a2[r]+=x*w2; }
        }
        #pragma unroll
        for (int r=0;r<10;r++){ sb1v[r][t]=fmaxf(a1[r],0.f); sb2v[r][t]=fmaxf(a2[r],0.f); }
        #pragma unroll
        for (int r=0;r<10;r++){ a1[r]=0.f; a2[r]=0.f; }
        #pragma unroll 4
        for (int k=0;k<256;k++){
            float w1 = aL1[k*256+t], w2 = aL2[k*256+t];
            #pragma unroll
            for (int r=0;r<10;r++){ float x=sla[r][k]; a1[r]+=x*w1; a2[r]+=x*w2; }
        }
        #pragma unroll
        for (int r=0;r<10;r++){ sb1a[r][t]=fmaxf(a1[r],0.f); sb2a[r][t]=fmaxf(a2[r],0.f); }
    }
    __syncthreads();

    if (t < 100){
        int v = t/10, a = t - v*10;
        float acc=0.f;
        for (int k=0;k<256;k++) acc += sb2v[v][k]*sb1a[a][k];
        satt[t] = fmaxf(acc*(1.0f/16.0f), 0.f);
    }
    __syncthreads();
    float thr = thrp[0];
    if (t < 10){
        int v = t;
        float rs=0.f; for(int a=0;a<10;a++) rs += satt[v*10+a];
        float inv = 1.f/(rs+1e-8f);
        float tmp[10]; float rs2=0.f;
        for(int a=0;a<10;a++){ float x = satt[v*10+a]*inv; x = (x>thr)?x:0.f; tmp[a]=x; rs2+=x; }
        float inv2 = 1.f/(rs2+1e-8f);
        for(int a=0;a<10;a++) s_v2a[v*10+a] = tmp[a]*inv2;
    } else if (t>=16 && t<26){
        int a = t-16;
        float cs=0.f; for(int v=0;v<10;v++) cs += satt[v*10+a];
        float inv = 1.f/(cs+1e-8f);
        float tmp[10]; float cs2=0.f;
        for(int v=0;v<10;v++){ float x = satt[v*10+a]*inv; x=(x>thr)?x:0.f; tmp[v]=x; cs2+=x; }
        float inv2 = 1.f/(cs2+1e-8f);
        for(int v=0;v<10;v++) s_a2v[a*10+v] = tmp[v]*inv2;
    }
    __syncthreads();

    #pragma unroll
    for (int v=0;v<10;v++){
        float acc = slv[v][t];
        #pragma unroll
        for (int a=0;a<10;a++) acc += s_v2a[v*10+a]*sb2a[a][t];
        slv[v][t] = acc;
    }
    #pragma unroll
    for (int a=0;a<10;a++){
        float acc = sla[a][t];
        #pragma unroll
        for (int v=0;v<10;v++) acc += s_a2v[a*10+v]*sb1v[v][t];
        sla[a][t] = acc;
    }
    __syncthreads();

    float fv[10], fa2[10];
    #pragma unroll
    for (int r=0;r<10;r++){ fv[r]=0.f; fa2[r]=0.f; }
    #pragma unroll 4
    for (int k=0;k<256;k++){
        float wv = vfc[k*256+t], wa = afc[k*256+t];
        #pragma unroll
        for (int r=0;r<10;r++){ fv[r]+=slv[r][k]*wv; fa2[r]+=sla[r][k]*wa; }
    }
    #pragma unroll
    for (int r=0;r<10;r++){ fv[r]=fmaxf(fv[r],0.f); fa2[r]=fmaxf(fa2[r],0.f); }

    #pragma unroll
    for (int r=0;r<10;r++){
        float s1 = wred64(fv[r]);
        float s2 = wred64(fv[r]*fv[r]);
        float s3 = wred64(fa2[r]);
        float s4 = wred64(fa2[r]*fa2[r]);
        if (lane==0){
            sredp[r*16 + 0*4 + w] = s1; sredp[r*16 + 1*4 + w] = s2;
            sredp[r*16 + 2*4 + w] = s3; sredp[r*16 + 3*4 + w] = s4;
        }
    }
    __syncthreads();
    float gt = ln_g[t], bt2 = ln_b[t];
    #pragma unroll
    for (int r=0;r<10;r++){
        float s1 = sredp[r*16+0]+sredp[r*16+1]+sredp[r*16+2]+sredp[r*16+3];
        float s2 = sredp[r*16+4]+sredp[r*16+5]+sredp[r*16+6]+sredp[r*16+7];
        float s3 = sredp[r*16+8]+sredp[r*16+9]+sredp[r*16+10]+sredp[r*16+11];
        float s4 = sredp[r*16+12]+sredp[r*16+13]+sredp[r*16+14]+sredp[r*16+15];
        float muv = s1*(1.f/256.f);
        float varv = s2*(1.f/256.f) - muv*muv;
        float rsv = 1.f/sqrtf(varv+1e-6f);
        float vln = (fv[r]-muv)*rsv*gt + bt2;
        float mua = s3*(1.f/256.f);
        float vara = s4*(1.f/256.f) - mua*mua;
        float rsa = 1.f/sqrtf(vara+1e-6f);
        float aln = (fa2[r]-mua)*rsa*gt + bt2;
        float fu = 0.5f*(vln+aln);
        dout[(size_t)(b*10+r)*256 + t] = fu;
        sfu[r][t] = fu;
        float c1 = wred64(vln*vln);
        float c2 = wred64(aln*aln);
        float c3 = wred64(vln*aln);
        if (lane==0){
            scos[r*12 + 0*4 + w] = c1; scos[r*12 + 1*4 + w] = c2; scos[r*12 + 2*4 + w] = c3;
        }
    }
    __syncthreads();
    if (t < 10){
        int r = t;
        float nv2 = scos[r*12+0]+scos[r*12+1]+scos[r*12+2]+scos[r*12+3];
        float na2 = scos[r*12+4]+scos[r*12+5]+scos[r*12+6]+scos[r*12+7];
        float dva = scos[r*12+8]+scos[r*12+9]+scos[r*12+10]+scos[r*12+11];
        float nv = fmaxf(sqrtf(nv2), 1e-12f);
        float na = fmaxf(sqrtf(na2), 1e-12f);
        dout[729600 + b*10 + r] = dva/(nv*na);
    }

    #pragma unroll
    for (int pass=0; pass<3; ++pass){
        int r = pass*4 + w;
        if (r < 10){
            float acc = 0.f;
            for (int k4=0;k4<64;k4++){
                float4 f4 = *(const float4*)&sfu[r][k4*4];
                acc += f4.x*L1w[(k4*4)*64+lane] + f4.y*L1w[(k4*4+1)*64+lane]
                     + f4.z*L1w[(k4*4+2)*64+lane] + f4.w*L1w[(k4*4+3)*64+lane];
            }
            s64[r][lane] = fmaxf(acc, 0.f);
        }
    }
    __syncthreads();
    for (int i=t; i<290; i+=256){
        int r = i/29, jj = i - r*29;
        float acc = 0.f;
        #pragma unroll
        for (int k=0;k<64;k++) acc += s64[r][k]*L2w[k*29+jj];
        dout[655360 + (size_t)(b*10+r)*29 + jj] = acc;
    }
}

// =======================================================================
extern "C" void kernel_launch(void* const* d_in, const int* in_sizes, int n_in,
                              void* d_out, int out_size, void* d_ws, size_t ws_size,
                              hipStream_t stream) {
    const float* audio  = (const float*)d_in[0];
    const float* video  = (const float*)d_in[1];
    const float* thrp   = (const float*)d_in[2];
    const float* fa_w1  = (const float*)d_in[3];
    const float* fa_w2  = (const float*)d_in[4];
    const float* av_aw  = (const float*)d_in[5];
    const float* av_ab  = (const float*)d_in[6];
    const float* av_vw  = (const float*)d_in[7];
    const float* av_vb  = (const float*)d_in[8];
    const float* av_v2w = (const float*)d_in[9];
    const float* av_gw  = (const float*)d_in[10];
    const float* av_hw  = (const float*)d_in[11];
    const float* fv_w1  = (const float*)d_in[12];
    const float* fv_w2  = (const float*)d_in[13];
    const float* la_wih = (const float*)d_in[14];
    const float* la_whh = (const float*)d_in[15];
    const float* la_b   = (const float*)d_in[16];
    const float* lv_wih = (const float*)d_in[17];
    const float* lv_whh = (const float*)d_in[18];
    const float* lv_b   = (const float*)d_in[19];
    const float* vL1    = (const float*)d_in[20];
    const float* vL2    = (const float*)d_in[21];
    const float* aL1    = (const float*)d_in[22];
    const float* aL2    = (const float*)d_in[23];
    const float* vfc    = (const float*)d_in[24];
    const float* afc    = (const float*)d_in[25];
    const float* ln_g   = (const float*)d_in[26];
    const float* ln_b   = (const float*)d_in[27];
    const float* L1w    = (const float*)d_in[28];
    const float* L2w    = (const float*)d_in[29];
    float* dout = (float*)d_out;
    float* ws = (float*)d_ws;

    // workspace layout (float offsets)
    float* faW  = ws;                 // 16384
    float* gGA  = ws + 409600;        // 125440
    float* vT   = ws + 535040;        // 1310720
    float* xpA  = ws + 2173440;       // 2621440
    float* xpV  = ws + 4794880;       // 2621440
    float* la   = ws + 7416320;       // 655360
    float* lv   = ws + 8071680;       // 655360
    _Float16* Bh = (_Float16*)(ws + 12659200);
    _Float16* Bl = (_Float16*)(ws + 12790272);
    _Float16* Wh = (_Float16*)(ws + 12921344);
    _Float16* Wl = (_Float16*)(ws + 12937728);
    _Float16* PKfv_h = (_Float16*)(ws + 12954112);
    _Float16* PKfv_l = (_Float16*)(ws + 12986880);
    _Float16* PKxv_h = (_Float16*)(ws + 13150720);
    _Float16* PKxv_l = (_Float16*)(ws + 13216256);

    k_prep<<<1984, 256, 0, stream>>>(fa_w1, fa_w2, faW, fv_w1, fv_w2,
                                     av_vw, Bh, Bl, av_v2w, Wh, Wl,
                                     lv_wih, PKfv_h, PKfv_l, PKxv_h, PKxv_l);
    k_faga2<<<320, 256, 0, stream>>>(audio, faW, av_aw, av_ab, av_gw,
                                     la_wih, la_b, gGA, xpA);
    k_avga_fused<<<2560, 256, 0, stream>>>(video, Bh, Bl, av_vb, Wh, Wl,
                                           gGA, av_hw, vT);
    k_gemm2<<<dim3(80,4), 256, 0, stream>>>(vT, PKfv_h, PKfv_l,
                                            PKxv_h, PKxv_l, lv_b, xpV);
    k_lstm<<<256, 256, 0, stream>>>(xpA, xpV, la_whh, lv_whh, la, lv);
    k_tail<<<256, 256, 0, stream>>>(la, lv, vL1, vL2, aL1, aL2, vfc, afc,
                                    thrp, ln_g, ln_b, L1w, L2w, dout);
}

// Round 13
// 638.344 us; speedup vs baseline: 1.1107x; 1.1107x over previous
//
#include <hip/hip_runtime.h>
#include <math.h>

#define DEV __device__ __forceinline__

typedef _Float16 f16x8 __attribute__((ext_vector_type(8)));
typedef _Float16 f16x4 __attribute__((ext_vector_type(4)));
typedef float    f32x4 __attribute__((ext_vector_type(4)));

DEV float sigmoidf_(float x){ return 1.0f/(1.0f + expf(-x)); }

DEV float wred64(float x){
    #pragma unroll
    for (int off=32; off; off>>=1) x += __shfl_xor(x, off);
    return x;
}

#define MFMA16(a,b,c) __builtin_amdgcn_mfma_f32_16x16x32_f16(a,b,c,0,0,0)

// ---------------- pack helper: frag layout, f16 hi/lo ------------------
DEV void packone(const float* __restrict__ src, int N, int NfrTot, int nfOff,
                 _Float16* __restrict__ Dh, _Float16* __restrict__ Dl, int o){
    int j = o&7, l16 = (o>>3)&15, kg = (o>>7)&3;
    int rest = o>>9;
    int nfl = rest % (N>>4), kt = rest / (N>>4);
    int k = kt*32 + kg*8 + j, n = nfl*16 + l16;
    float x = src[(size_t)k*N + n];
    _Float16 h = (_Float16)x;
    size_t d = ((size_t)kt*NfrTot + nfOff + nfl)*512 + kg*128 + l16*8 + j;
    Dh[d] = h; Dl[d] = (_Float16)(x - (float)h);
}

// ---------------- merged prep: faW, Bh/Bl, Wh/Wl, PKfv, PKxv -----------
__global__ __launch_bounds__(256) void k_prep(
    const float* __restrict__ fa_w1, const float* __restrict__ fa_w2, float* __restrict__ faW,
    const float* __restrict__ fv_w1, const float* __restrict__ fv_w2,
    const float* __restrict__ av_vw, _Float16* __restrict__ Bh, _Float16* __restrict__ Bl,
    const float* __restrict__ v2w, _Float16* __restrict__ Wh, _Float16* __restrict__ Wl,
    const float* __restrict__ lv_wih,
    _Float16* __restrict__ PKfv_h, _Float16* __restrict__ PKfv_l,
    _Float16* __restrict__ PKxv_h, _Float16* __restrict__ PKxv_l)
{
    int bid = blockIdx.x, t = threadIdx.x;
    if (bid < 64){
        int idx = bid*256+t; int m = idx>>7, n = idx&127;
        float acc=0.f;
        for (int k=0;k<256;k++) acc += fa_w1[m*256+k]*fa_w2[k*128+n];
        faW[idx]=acc;
    } else if (bid < 1088){
        int o = (bid-64)*256+t;
        int j = o & 7, l16 = (o>>3)&15, kg = (o>>7)&3, nf = (o>>9)&31, kt = o>>14;
        int k = kt*32 + kg*8 + j, n = nf*16 + l16;
        float x = av_vw[(size_t)k*512 + n];
        _Float16 h = (_Float16)x;
        Bh[o] = h; Bl[o] = (_Float16)(x - (float)h);
    } else if (bid < 1216){
        int o = (bid-1088)*256+t;
        int j = o & 7, l16 = (o>>3)&15, kg = (o>>7)&3, qf = (o>>9)&3, kbg = o>>11;
        int k = kbg*32 + kg*8 + j, q = qf*16 + l16;
        float x = (q < 49) ? v2w[(size_t)k*49 + q] : 0.f;
        _Float16 h = (_Float16)x;
        Wh[o] = h; Wl[o] = (_Float16)(x - (float)h);
    } else if (bid < 1472){
        int o = (bid-1216)*256+t;
        int j=o&7, l16=(o>>3)&15, kg=(o>>7)&3; int rest=o>>9;
        int nfl = rest&7, kt = rest>>3;
        int k = kt*32+kg*8+j, n = nfl*16+l16;
        float acc=0.f;
        for (int kk=0;kk<256;kk++) acc += fv_w1[k*256+kk]*fv_w2[kk*128+n];
        _Float16 h=(_Float16)acc;
        size_t d = ((size_t)kt*8 + nfl)*512 + kg*128 + l16*8 + j;
        PKfv_h[d]=h; PKfv_l[d]=(_Float16)(acc-(float)h);
    } else {
        int seg = (bid-1472)>>8;
        int o = ((bid-1472)&255)*256+t;
        packone(lv_wih + (size_t)seg*65536, 512, 64, seg*32, PKxv_h, PKxv_l, o);
    }
}

// ---------------- fused fa + a_h + ga + xpA, 8 bt per block ------------
__global__ __launch_bounds__(256) void k_faga2(
    const float* __restrict__ audio, const float* __restrict__ faW,
    const float* __restrict__ av_aw, const float* __restrict__ av_ab,
    const float* __restrict__ av_gw,
    const float* __restrict__ la_wih, const float* __restrict__ la_b,
    float* __restrict__ gGA, float* __restrict__ xpA)
{
    int b0 = blockIdx.x*8; int t = threadIdx.x;
    __shared__ float sau[8][128], sfa[8][128], sah[8][512];
    for (int i=t;i<1024;i+=256){ int bt=i>>7,k=i&127; sau[bt][k]=audio[(size_t)(b0+bt)*128+k]; }
    __syncthreads();
    for (int u=0;u<4;u++){
        int i=t+u*256, bt=i>>7, n=i&127;
        float acc=0.f;
        for (int k4=0;k4<32;k4++){
            float4 x4=*(const float4*)&sau[bt][k4*4];
            acc+=x4.x*faW[(k4*4)*128+n]+x4.y*faW[(k4*4+1)*128+n]
                +x4.z*faW[(k4*4+2)*128+n]+x4.w*faW[(k4*4+3)*128+n];
        }
        sfa[bt][n]=acc;
    }
    __syncthreads();
    for (int u=0;u<2;u++){
        int n=t+u*256;
        float bv=av_ab[n];
        float acc[8]={bv,bv,bv,bv,bv,bv,bv,bv};
        for (int k4=0;k4<32;k4++){
            float w0=av_aw[(k4*4)*512+n], w1=av_aw[(k4*4+1)*512+n],
                  w2=av_aw[(k4*4+2)*512+n], w3=av_aw[(k4*4+3)*512+n];
            #pragma unroll
            for (int bt=0;bt<8;bt++){
                float4 x4=*(const float4*)&sfa[bt][k4*4];
                acc[bt]+=x4.x*w0+x4.y*w1+x4.z*w2+x4.w*w3;
            }
        }
        #pragma unroll
        for (int bt=0;bt<8;bt++) sah[bt][n]=fmaxf(acc[bt],0.f);
    }
    __syncthreads();
    for (int hh=0;hh<2;hh++){
        if (t<196){
            int bt=hh*4 + t/49, q=t%49;
            float acc=0.f;
            for (int k=0;k<512;k++) acc+=sah[bt][k]*av_gw[k*49+q];
            gGA[(size_t)(b0+bt)*49+q]=acc;
        }
    }
    for (int u=0;u<4;u++){
        int n = t + u*256;
        int dir = n >> 9, g = n & 511;
        const float* W = la_wih + (size_t)dir*65536;
        float bvv = la_b[dir*512 + g];
        float acc[8] = {bvv,bvv,bvv,bvv,bvv,bvv,bvv,bvv};
        for (int k4=0;k4<32;k4++){
            float w0=W[(k4*4+0)*512+g], w1=W[(k4*4+1)*512+g],
                  w2=W[(k4*4+2)*512+g], w3=W[(k4*4+3)*512+g];
            #pragma unroll
            for (int bt=0;bt<8;bt++){
                float4 x4=*(const float4*)&sfa[bt][k4*4];
                acc[bt]+=x4.x*w0+x4.y*w1+x4.z*w2+x4.w*w3;
            }
        }
        #pragma unroll
        for (int bt=0;bt<8;bt++)
            xpA[((size_t)(b0+bt))*1024 + n] = acc[bt];
    }
}

// ---------------- fully fused AVGA: proven round-7 structure -----------
DEV void cvt4_(float4 v, f16x4& hv, f16x4& lv){
    hv[0]=(_Float16)v.x; lv[0]=(_Float16)(v.x-(float)hv[0]);
    hv[1]=(_Float16)v.y; lv[1]=(_Float16)(v.y-(float)hv[1]);
    hv[2]=(_Float16)v.z; lv[2]=(_Float16)(v.z-(float)hv[2]);
    hv[3]=(_Float16)v.w; lv[3]=(_Float16)(v.w-(float)hv[3]);
}

__global__ __launch_bounds__(256,2) void k_avga_fused(
    const float* __restrict__ video,
    const _Float16* __restrict__ Bh, const _Float16* __restrict__ Bl,
    const float* __restrict__ bias,
    const _Float16* __restrict__ Wh, const _Float16* __restrict__ Wl,
    const float* __restrict__ gGA, const float* __restrict__ hw,
    float* __restrict__ vT)
{
    __shared__ __align__(16) char smem[67072];
    int bt = blockIdx.x;
    int t = threadIdx.x;
    int lane = t & 63, w = t >> 6;
    int l16 = lane & 15, lq = lane >> 4;
    int lb = lane * 16;

    int am = t >> 3, ak = (t & 7) * 4;
    int aoff1 = ((am>>4)*4 + (ak>>3))*256 + (am&15)*16 + (ak&7)*2;
    int am2 = am + 32;
    int aoff2 = ((am2>>4)*4 + (ak>>3))*256 + (am2&15)*16 + (ak&7)*2;
    size_t r1 = (size_t)bt*49 + am;  if (r1 > 125439) r1 = 125439;
    size_t r2 = (size_t)bt*49 + am2; if (r2 > 125439) r2 = 125439;
    const float* Arow1 = video + r1*512 + ak;
    const float* Arow2 = video + r2*512 + ak;

    const f32x4 vzero = {0.f,0.f,0.f,0.f};
    f32x4 acc[4][8];
    #pragma unroll
    for (int p=0;p<4;p++)
        #pragma unroll
        for (int q=0;q<8;q++) acc[p][q] = vzero;

    float4 pa0, pa1;
    pa0 = *(const float4*)(Arow1);
    pa1 = *(const float4*)(Arow2);
    {
        f16x4 hv, lv;
        char* h = &smem[0];
        cvt4_(pa0, hv, lv);
        *(f16x4*)(h + aoff1) = hv; *(f16x4*)(h + 4096 + aoff1) = lv;
        cvt4_(pa1, hv, lv);
        *(f16x4*)(h + aoff2) = hv; *(f16x4*)(h + 4096 + aoff2) = lv;
    }
    __syncthreads();

    for (int kt = 0; kt < 16; ++kt){
        int cur = kt & 1;
        bool more = (kt < 15);
        if (more){
            pa0 = *(const float4*)(Arow1 + (kt+1)*32);
            pa1 = *(const float4*)(Arow2 + (kt+1)*32);
        }
        const char* aB = &smem[cur*8192];
        f16x8 ah[4], al[4];
        #pragma unroll
        for (int p=0;p<4;p++){
            ah[p] = *(const f16x8*)(aB + p*1024 + lb);
            al[p] = *(const f16x8*)(aB + 4096 + p*1024 + lb);
        }
        #pragma unroll
        for (int q=0;q<8;q++){
            size_t bo = (size_t)kt*16384 + (size_t)(w*8 + q)*512 + lane*8;
            f16x8 bh  = *(const f16x8*)(Bh + bo);
            f16x8 bl2 = *(const f16x8*)(Bl + bo);
            #pragma unroll
            for (int p=0;p<4;p++){
                acc[p][q] = MFMA16(ah[p], bh,  acc[p][q]);
                acc[p][q] = MFMA16(ah[p], bl2, acc[p][q]);
                acc[p][q] = MFMA16(al[p], bh,  acc[p][q]);
            }
        }
        if (more){
            char* h = &smem[(cur^1)*8192];
            f16x4 hv, lv;
            cvt4_(pa0, hv, lv);
            *(f16x4*)(h + aoff1) = hv; *(f16x4*)(h + 4096 + aoff1) = lv;
            cvt4_(pa1, hv, lv);
            *(f16x4*)(h + aoff2) = hv; *(f16x4*)(h + 4096 + aoff2) = lv;
        }
        __syncthreads();
    }

    // ---- epilogue: per-wave VH (bias+relu, f16 hi/lo) + content MFMA --
    float bv[8];
    #pragma unroll
    for (int q=0;q<8;q++) bv[q] = bias[w*128 + q*16 + l16];

    char* vh = &smem[16384 + w*8192];
    f32x4 cacc[4][4];
    #pragma unroll
    for (int p=0;p<4;p++)
        #pragma unroll
        for (int qf=0;qf<4;qf++) cacc[p][qf] = vzero;

    #pragma unroll
    for (int c=0;c<4;c++){
        #pragma unroll
        for (int p=0;p<4;p++)
            #pragma unroll
            for (int qq=0;qq<2;qq++){
                int q = c*2 + qq;
                int offbase = p*1024 + (qq*2 + (l16>>3))*256 + (l16&7)*2;
                #pragma unroll
                for (int r=0;r<4;r++){
                    float x = fmaxf(acc[p][q][r] + bv[q], 0.f);
                    _Float16 hh = (_Float16)x;
                    _Float16 ll = (_Float16)(x - (float)hh);
                    int off = offbase + (lq*4 + r)*16;
                    *(_Float16*)(vh + off)        = hh;
                    *(_Float16*)(vh + 4096 + off) = ll;
                }
            }
        int kbg = w*4 + c;
        f16x8 vhh[4], vhl[4];
        #pragma unroll
        for (int p=0;p<4;p++){
            vhh[p] = *(const f16x8*)(vh + p*1024 + lb);
            vhl[p] = *(const f16x8*)(vh + 4096 + p*1024 + lb);
        }
        #pragma unroll
        for (int qf=0;qf<4;qf++){
            size_t wo = (size_t)kbg*2048 + qf*512 + lane*8;
            f16x8 wh = *(const f16x8*)(Wh + wo);
            f16x8 wl = *(const f16x8*)(Wl + wo);
            #pragma unroll
            for (int p=0;p<4;p++){
                cacc[p][qf] = MFMA16(vhh[p], wh, cacc[p][qf]);
                cacc[p][qf] = MFMA16(vhh[p], wl, cacc[p][qf]);
                cacc[p][qf] = MFMA16(vhl[p], wh, cacc[p][qf]);
            }
        }
    }

    // ---- cross-wave content reduce (4-buffer parallel) ----
    __syncthreads();
    float* pw = (float*)&smem[w*16384];
    #pragma unroll
    for (int p=0;p<4;p++)
        #pragma unroll
        for (int qf=0;qf<4;qf++)
            #pragma unroll
            for (int r=0;r<4;r++)
                pw[(p*16 + lq*4 + r)*64 + qf*16 + l16] = cacc[p][qf][r];
    __syncthreads();
    float* cb = (float*)&smem[0];
    for (int i=t; i<4096; i+=256)
        cb[i] = cb[i] + cb[4096+i] + cb[8192+i] + cb[12288+i];
    __syncthreads();

    // ---- z, softmax, weighted sum ----
    float* szp    = (float*)&smem[65536];
    float* salpha = (float*)&smem[66560];
    if (t < 196){
        int p = t >> 2, ds = t & 3;
        float ga = gGA[(size_t)bt*49 + p];
        float part = 0.f;
        for (int q = ds*13; q < ds*13+13 && q < 49; q++)
            part += tanhf(cb[p*64 + q] + ga) * hw[q];
        szp[t] = part;
    }
    __syncthreads();
    if (t < 64){
        float z = (t<49) ? (szp[t*4]+szp[t*4+1]+szp[t*4+2]+szp[t*4+3]) : -1e30f;
        float m = z;
        #pragma unroll
        for (int off=32; off; off>>=1) m = fmaxf(m, __shfl_xor(m, off));
        float e = (t<49)? expf(z - m) : 0.f;
        float s = e;
        #pragma unroll
        for (int off=32; off; off>>=1) s += __shfl_xor(s, off);
        salpha[t] = e / s;
    }
    __syncthreads();
    const float* vb = video + (size_t)bt*49*512;
    #pragma unroll
    for (int u=0;u<2;u++){
        int d = t + u*256;
        float a0 = 0.f;
        for (int p=0;p<49;p++) a0 += salpha[p] * vb[(size_t)p*512 + d];
        vT[(size_t)bt*512 + d] = a0;
    }
}

// ---------------- fused vfea + xpV GEMM (two-phase, MFMA) --------------
__global__ __launch_bounds__(256) void k_gemm2(
    const float* __restrict__ vT,
    const _Float16* __restrict__ Fh, const _Float16* __restrict__ Fl,
    const _Float16* __restrict__ Xh, const _Float16* __restrict__ Xl,
    const float* __restrict__ lv_b,
    float* __restrict__ xpV)
{
    __shared__ __align__(16) char sA[2][4096];
    __shared__ float sV[32][132];
    int t = threadIdx.x, lane = t&63, w = t>>6;
    int l16 = lane&15, lq = lane>>4, lb = lane*16;
    int row0 = blockIdx.x * 32;

    int am = t>>3, ak = (t&7)*4;
    int aoff = ((am>>4)*4 + (ak>>3))*256 + (am&15)*16 + (ak&7)*2;
    const float* Arow = vT + (size_t)(row0+am)*512 + ak;

    const f32x4 vzero = {0.f,0.f,0.f,0.f};
    f32x4 acc1[2][2];
    #pragma unroll
    for (int p=0;p<2;p++)
        #pragma unroll
        for (int q=0;q<2;q++) acc1[p][q] = vzero;

    float4 pa = *(const float4*)(Arow);
    {
        f16x4 hv, lv;
        char* h = &sA[0][0];
        cvt4_(pa, hv, lv);
        *(f16x4*)(h + aoff) = hv; *(f16x4*)(h + 2048 + aoff) = lv;
    }
    __syncthreads();
    for (int kt = 0; kt < 16; ++kt){
        int cur = kt & 1;
        bool more = (kt < 15);
        if (more) pa = *(const float4*)(Arow + (kt+1)*32);
        const char* aB = &sA[cur][0];
        f16x8 ah[2], al[2];
        #pragma unroll
        for (int p=0;p<2;p++){
            ah[p] = *(const f16x8*)(aB + p*1024 + lb);
            al[p] = *(const f16x8*)(aB + 2048 + p*1024 + lb);
        }
        #pragma unroll
        for (int q=0;q<2;q++){
            size_t bo = ((size_t)kt*8 + w*2 + q)*512 + lane*8;
            f16x8 bh  = *(const f16x8*)(Fh + bo);
            f16x8 bl2 = *(const f16x8*)(Fl + bo);
            #pragma unroll
            for (int p=0;p<2;p++){
                acc1[p][q] = MFMA16(ah[p], bh,  acc1[p][q]);
                acc1[p][q] = MFMA16(ah[p], bl2, acc1[p][q]);
                acc1[p][q] = MFMA16(al[p], bh,  acc1[p][q]);
            }
        }
        if (more){
            char* h = &sA[cur^1][0];
            f16x4 hv, lv;
            cvt4_(pa, hv, lv);
            *(f16x4*)(h + aoff) = hv; *(f16x4*)(h + 2048 + aoff) = lv;
        }
        __syncthreads();
    }
    #pragma unroll
    for (int q=0;q<2;q++){
        int n = (w*2+q)*16 + l16;
        #pragma unroll
        for (int p=0;p<2;p++)
            #pragma unroll
            for (int r=0;r<4;r++)
                sV[p*16 + lq*4 + r][n] = acc1[p][q][r];
    }
    __syncthreads();

    int nf0 = blockIdx.y*16 + w*4;
    f32x4 acc2[2][4];
    #pragma unroll
    for (int p=0;p<2;p++)
        #pragma unroll
        for (int q=0;q<4;q++) acc2[p][q] = vzero;

    pa = *(const float4*)&sV[am][ak];
    {
        f16x4 hv, lv;
        char* h = &sA[0][0];
        cvt4_(pa, hv, lv);
        *(f16x4*)(h + aoff) = hv; *(f16x4*)(h + 2048 + aoff) = lv;
    }
    __syncthreads();
    for (int kt = 0; kt < 4; ++kt){
        int cur = kt & 1;
        bool more = (kt < 3);
        if (more) pa = *(const float4*)&sV[am][(kt+1)*32 + ak];
        const char* aB = &sA[cur][0];
        f16x8 ah[2], al[2];
        #pragma unroll
        for (int p=0;p<2;p++){
            ah[p] = *(const f16x8*)(aB + p*1024 + lb);
            al[p] = *(const f16x8*)(aB + 2048 + p*1024 + lb);
        }
        #pragma unroll
        for (int q=0;q<4;q++){
            size_t bo = ((size_t)kt*64 + nf0 + q)*512 + lane*8;
            f16x8 bh  = *(const f16x8*)(Xh + bo);
            f16x8 bl2 = *(const f16x8*)(Xl + bo);
            #pragma unroll
            for (int p=0;p<2;p++){
                acc2[p][q] = MFMA16(ah[p], bh,  acc2[p][q]);
                acc2[p][q] = MFMA16(ah[p], bl2, acc2[p][q]);
                acc2[p][q] = MFMA16(al[p], bh,  acc2[p][q]);
            }
        }
        if (more){
            char* h = &sA[cur^1][0];
            f16x4 hv, lv;
            cvt4_(pa, hv, lv);
            *(f16x4*)(h + aoff) = hv; *(f16x4*)(h + 2048 + aoff) = lv;
        }
        __syncthreads();
    }
    #pragma unroll
    for (int q=0;q<4;q++){
        int n = (nf0+q)*16 + l16;
        float bv = lv_b[n];
        #pragma unroll
        for (int p=0;p<2;p++){
            #pragma unroll
            for (int r=0;r<4;r++)
                xpV[(size_t)(row0 + p*16 + lq*4 + r)*1024 + n] = acc2[p][q][r] + bv;
        }
    }
}

// ---------------- persistent bidirectional LSTMs (256 blocks) ----------
__global__ __launch_bounds__(256) void k_lstm(
    const float* __restrict__ xpA, const float* __restrict__ xpV,
    const float* __restrict__ la_whh, const float* __restrict__ lv_whh,
    float* __restrict__ lstm_a, float* __restrict__ lstm_v)
{
    int blk = blockIdx.x;
    int c = blk >> 6;
    int chunk = blk & 63;
    int t = threadIdx.x;
    int j  = t & 127;
    int bh = t >> 7;
    const float* whh = ((c<2)? la_whh : lv_whh) + (size_t)(c&1)*128*512;
    const float* xpm = (c<2)? xpA : xpV;
    float* outp = (c<2)? lstm_a : lstm_v;
    int dir = c & 1;

    __shared__ float hbuf[4][128];
    float cc[2] = {0.f,0.f};
    for (int i=t;i<512;i+=256) ((float*)hbuf)[i] = 0.f;
    __syncthreads();

    for (int s=0; s<10; s++){
        int tt = dir ? (9-s) : s;
        float gi[2], gf[2], gg[2], go[2];
        #pragma unroll
        for (int b=0;b<2;b++){
            int gb = chunk*4 + bh*2 + b;
            const float* xrow = xpm + ((size_t)gb*10 + tt)*1024 + dir*512;
            gi[b]=xrow[j]; gf[b]=xrow[128+j]; gg[b]=xrow[256+j]; go[b]=xrow[384+j];
        }
        #pragma unroll 4
        for (int k=0;k<128;k++){
            float wi = whh[k*512 + j];
            float wf = whh[k*512 + 128 + j];
            float wg = whh[k*512 + 256 + j];
            float wo = whh[k*512 + 384 + j];
            #pragma unroll
            for (int b=0;b<2;b++){
                float hk = hbuf[bh*2+b][k];
                gi[b] += hk*wi; gf[b] += hk*wf; gg[b] += hk*wg; go[b] += hk*wo;
            }
        }
        __syncthreads();
        #pragma unroll
        for (int b=0;b<2;b++){
            float i_ = sigmoidf_(gi[b]);
            float f_ = sigmoidf_(gf[b]);
            float g_ = tanhf(gg[b]);
            float o_ = sigmoidf_(go[b]);
            cc[b] = f_*cc[b] + i_*g_;
            float h_ = o_*tanhf(cc[b]);
            hbuf[bh*2+b][j] = h_;
            int gb = chunk*4 + bh*2 + b;
            outp[((size_t)gb*10 + tt)*256 + dir*128 + j] = h_;
        }
        __syncthreads();
    }
}

// ---------------- per-sample tail (512 threads, row-split halves) ------
__global__ __launch_bounds__(512) void k_tail(
    const float* __restrict__ lstm_a, const float* __restrict__ lstm_v,
    const float* __restrict__ vL1, const float* __restrict__ vL2,
    const float* __restrict__ aL1, const float* __restrict__ aL2,
    const float* __restrict__ vfc, const float* __restrict__ afc,
    const float* __restrict__ thrp,
    const float* __restrict__ ln_g, const float* __restrict__ ln_b,
    const float* __restrict__ L1w, const float* __restrict__ L2w,
    float* __restrict__ dout)
{
    int b = blockIdx.x, tid = threadIdx.x;
    int t = tid & 255;            // column 0..255
    int half = tid >> 8;          // 0/1: owns rows half*5 .. half*5+4
    int lane = tid & 63, w = tid >> 6;   // w 0..7
    int wl = w & 3;               // wave index within half
    int r0 = half*5;

    __shared__ float sla[10][256], slv[10][256];
    __shared__ float sb1v[10][256], sb2v[10][256], sb1a[10][256], sb2a[10][256];
    __shared__ float sfu[10][256];
    __shared__ float s64[10][64];
    __shared__ float satt[100], s_v2a[100], s_a2v[100];
    __shared__ float sredp[10][4][4];
    __shared__ float scos[10][3][4];

    size_t base = (size_t)b*2560;
    for (int i=tid;i<2560;i+=512){
        ((float*)sla)[i] = lstm_a[base+i];
        ((float*)slv)[i] = lstm_v[base+i];
    }
    __syncthreads();

    // ---- branch GEMMs (f32 exact), 5 rows per half ----
    {
        float a1[5], a2[5];
        #pragma unroll
        for (int r=0;r<5;r++){ a1[r]=0.f; a2[r]=0.f; }
        #pragma unroll 4
        for (int k=0;k<256;k++){
            float w1 = vL1[k*256+t], w2 = vL2[k*256+t];
            #pragma unroll
            for (int r=0;r<5;r++){ float x=slv[r0+r][k]; a1[r]+=x*w1; a2[r]+=x*w2; }
        }
        #pragma unroll
        for (int r=0;r<5;r++){ sb1v[r0+r][t]=fmaxf(a1[r],0.f); sb2v[r0+r][t]=fmaxf(a2[r],0.f); }
        #pragma unroll
        for (int r=0;r<5;r++){ a1[r]=0.f; a2[r]=0.f; }
        #pragma unroll 4
        for (int k=0;k<256;k++){
            float w1 = aL1[k*256+t], w2 = aL2[k*256+t];
            #pragma unroll
            for (int r=0;r<5;r++){ float x=sla[r0+r][k]; a1[r]+=x*w1; a2[r]+=x*w2; }
        }
        #pragma unroll
        for (int r=0;r<5;r++){ sb1a[r0+r][t]=fmaxf(a1[r],0.f); sb2a[r0+r][t]=fmaxf(a2[r],0.f); }
    }
    __syncthreads();

    // ---- att + norm-thr ----
    if (tid < 100){
        int v = tid/10, a = tid - v*10;
        float acc=0.f;
        for (int k=0;k<256;k++) acc += sb2v[v][k]*sb1a[a][k];
        satt[tid] = fmaxf(acc*(1.0f/16.0f), 0.f);
    }
    __syncthreads();
    float thr = thrp[0];
    if (tid < 10){
        int v = tid;
        float rs=0.f; for(int a=0;a<10;a++) rs += satt[v*10+a];
        float inv = 1.f/(rs+1e-8f);
        float tmp[10]; float rs2=0.f;
        for(int a=0;a<10;a++){ float x = satt[v*10+a]*inv; x = (x>thr)?x:0.f; tmp[a]=x; rs2+=x; }
        float inv2 = 1.f/(rs2+1e-8f);
        for(int a=0;a<10;a++) s_v2a[v*10+a] = tmp[a]*inv2;
    } else if (tid>=16 && tid<26){
        int a = tid-16;
        float cs=0.f; for(int v=0;v<10;v++) cs += satt[v*10+a];
        float inv = 1.f/(cs+1e-8f);
        float tmp[10]; float cs2=0.f;
        for(int v=0;v<10;v++){ float x = satt[v*10+a]*inv; x=(x>thr)?x:0.f; tmp[v]=x; cs2+=x; }
        float inv2 = 1.f/(cs2+1e-8f);
        for(int v=0;v<10;v++) s_a2v[a*10+v] = tmp[v]*inv2;
    }
    __syncthreads();

    // ---- psp residuals (in-place, own rows only) ----
    #pragma unroll
    for (int v=0;v<5;v++){
        int row = r0+v;
        float acc = slv[row][t];
        #pragma unroll
        for (int a=0;a<10;a++) acc += s_v2a[row*10+a]*sb2a[a][t];
        slv[row][t] = acc;
    }
    #pragma unroll
    for (int a=0;a<5;a++){
        int row = r0+a;
        float acc = sla[row][t];
        #pragma unroll
        for (int v=0;v<10;v++) acc += s_a2v[row*10+v]*sb1v[v][t];
        sla[row][t] = acc;
    }
    __syncthreads();

    // ---- vfc/afc GEMM (f32) + relu, own rows ----
    float fv[5], fa2[5];
    #pragma unroll
    for (int r=0;r<5;r++){ fv[r]=0.f; fa2[r]=0.f; }
    #pragma unroll 4
    for (int k=0;k<256;k++){
        float wv = vfc[k*256+t], wa = afc[k*256+t];
        #pragma unroll
        for (int r=0;r<5;r++){ fv[r]+=slv[r0+r][k]*wv; fa2[r]+=sla[r0+r][k]*wa; }
    }
    #pragma unroll
    for (int r=0;r<5;r++){ fv[r]=fmaxf(fv[r],0.f); fa2[r]=fmaxf(fa2[r],0.f); }

    // ---- LN partials ----
    #pragma unroll
    for (int r=0;r<5;r++){
        float s1 = wred64(fv[r]);
        float s2 = wred64(fv[r]*fv[r]);
        float s3 = wred64(fa2[r]);
        float s4 = wred64(fa2[r]*fa2[r]);
        if (lane==0){
            sredp[r0+r][0][wl] = s1; sredp[r0+r][1][wl] = s2;
            sredp[r0+r][2][wl] = s3; sredp[r0+r][3][wl] = s4;
        }
    }
    __syncthreads();
    float gt = ln_g[t], bt2 = ln_b[t];
    #pragma unroll
    for (int r=0;r<5;r++){
        int row = r0+r;
        float s1 = sredp[row][0][0]+sredp[row][0][1]+sredp[row][0][2]+sredp[row][0][3];
        float s2 = sredp[row][1][0]+sredp[row][1][1]+sredp[row][1][2]+sredp[row][1][3];
        float s3 = sredp[row][2][0]+sredp[row][2][1]+sredp[row][2][2]+sredp[row][2][3];
        float s4 = sredp[row][3][0]+sredp[row][3][1]+sredp[row][3][2]+sredp[row][3][3];
        float muv = s1*(1.f/256.f);
        float varv = s2*(1.f/256.f) - muv*muv;
        float rsv = 1.f/sqrtf(varv+1e-6f);
        float vln = (fv[r]-muv)*rsv*gt + bt2;
        float mua = s3*(1.f/256.f);
        float vara = s4*(1.f/256.f) - mua*mua;
        float rsa = 1.f/sqrtf(vara+1e-6f);
        float aln = (fa2[r]-mua)*rsa*gt + bt2;
        float fu = 0.5f*(vln+aln);
        dout[(size_t)(b*10+row)*256 + t] = fu;
        sfu[row][t] = fu;
        float c1 = wred64(vln*vln);
        float c2 = wred64(aln*aln);
        float c3 = wred64(vln*aln);
        if (lane==0){
            scos[row][0][wl] = c1; scos[row][1][wl] = c2; scos[row][2][wl] = c3;
        }
    }
    __syncthreads();
    if (tid < 10){
        int r = tid;
        float nv2 = scos[r][0][0]+scos[r][0][1]+scos[r][0][2]+scos[r][0][3];
        float na2 = scos[r][1][0]+scos[r][1][1]+scos[r][1][2]+scos[r][1][3];
        float dva = scos[r][2][0]+scos[r][2][1]+scos[r][2][2]+scos[r][2][3];
        float nv = fmaxf(sqrtf(nv2), 1e-12f);
        float na = fmaxf(sqrtf(na2), 1e-12f);
        dout[729600 + b*10 + r] = dva/(nv*na);
    }

    // ---- MLP: 10 rows over 8 waves ----
    #pragma unroll
    for (int pass=0; pass<2; ++pass){
        int r = pass*8 + w;
        if (r < 10){
            float acc = 0.f;
            for (int k4=0;k4<64;k4++){
                float4 f4 = *(const float4*)&sfu[r][k4*4];
                acc += f4.x*L1w[(k4*4)*64+lane] + f4.y*L1w[(k4*4+1)*64+lane]
                     + f4.z*L1w[(k4*4+2)*64+lane] + f4.w*L1w[(k4*4+3)*64+lane];
            }
            s64[r][lane] = fmaxf(acc, 0.f);
        }
    }
    __syncthreads();
    for (int i=tid; i<290; i+=512){
        int r = i/29, jj = i - r*29;
        float acc = 0.f;
        #pragma unroll
        for (int k=0;k<64;k++) acc += s64[r][k]*L2w[k*29+jj];
        dout[655360 + (size_t)(b*10+r)*29 + jj] = acc;
    }
}

// =======================================================================
extern "C" void kernel_launch(void* const* d_in, const int* in_sizes, int n_in,
                              void* d_out, int out_size, void* d_ws, size_t ws_size,
                              hipStream_t stream) {
    const float* audio  = (const float*)d_in[0];
    const float* video  = (const float*)d_in[1];
    const float* thrp   = (const float*)d_in[2];
    const float* fa_w1  = (const float*)d_in[3];
    const float* fa_w2  = (const float*)d_in[4];
    const float* av_aw  = (const float*)d_in[5];
    const float* av_ab  = (const float*)d_in[6];
    const float* av_vw  = (const float*)d_in[7];
    const float* av_vb  = (const float*)d_in[8];
    const float* av_v2w = (const float*)d_in[9];
    const float* av_gw  = (const float*)d_in[10];
    const float* av_hw  = (const float*)d_in[11];
    const float* fv_w1  = (const float*)d_in[12];
    const float* fv_w2  = (const float*)d_in[13];
    const float* la_wih = (const float*)d_in[14];
    const float* la_whh = (const float*)d_in[15];
    const float* la_b   = (const float*)d_in[16];
    const float* lv_wih = (const float*)d_in[17];
    const float* lv_whh = (const float*)d_in[18];
    const float* lv_b   = (const float*)d_in[19];
    const float* vL1    = (const float*)d_in[20];
    const float* vL2    = (const float*)d_in[21];
    const float* aL1    = (const float*)d_in[22];
    const float* aL2    = (const float*)d_in[23];
    const float* vfc    = (const float*)d_in[24];
    const float* afc    = (const float*)d_in[25];
    const float* ln_g   = (const float*)d_in[26];
    const float* ln_b   = (const float*)d_in[27];
    const float* L1w    = (const float*)d_in[28];
    const float* L2w    = (const float*)d_in[29];
    float* dout = (float*)d_out;
    float* ws = (float*)d_ws;

    // workspace layout (float offsets)
    float* faW  = ws;                 // 16384
    float* gGA  = ws + 409600;        // 125440
    float* vT   = ws + 535040;        // 1310720
    float* xpA  = ws + 2173440;       // 2621440
    float* xpV  = ws + 4794880;       // 2621440
    float* la   = ws + 7416320;       // 655360
    float* lv   = ws + 8071680;       // 655360
    _Float16* Bh = (_Float16*)(ws + 12659200);
    _Float16* Bl = (_Float16*)(ws + 12790272);
    _Float16* Wh = (_Float16*)(ws + 12921344);
    _Float16* Wl = (_Float16*)(ws + 12937728);
    _Float16* PKfv_h = (_Float16*)(ws + 12954112);
    _Float16* PKfv_l = (_Float16*)(ws + 12986880);
    _Float16* PKxv_h = (_Float16*)(ws + 13150720);
    _Float16* PKxv_l = (_Float16*)(ws + 13216256);

    k_prep<<<1984, 256, 0, stream>>>(fa_w1, fa_w2, faW, fv_w1, fv_w2,
                                     av_vw, Bh, Bl, av_v2w, Wh, Wl,
                                     lv_wih, PKfv_h, PKfv_l, PKxv_h, PKxv_l);
    k_faga2<<<320, 256, 0, stream>>>(audio, faW, av_aw, av_ab, av_gw,
                                     la_wih, la_b, gGA, xpA);
    k_avga_fused<<<2560, 256, 0, stream>>>(video, Bh, Bl, av_vb, Wh, Wl,
                                           gGA, av_hw, vT);
    k_gemm2<<<dim3(80,4), 256, 0, stream>>>(vT, PKfv_h, PKfv_l,
                                            PKxv_h, PKxv_l, lv_b, xpV);
    k_lstm<<<256, 256, 0, stream>>>(xpA, xpV, la_whh, lv_whh, la, lv);
    k_tail<<<256, 512, 0, stream>>>(la, lv, vL1, vL2, aL1, aL2, vfc, afc,
                                    thrp, ln_g, ln_b, L1w, L2w, dout);
}

// Round 14
// 604.314 us; speedup vs baseline: 1.1732x; 1.0563x over previous
//
#include <hip/hip_runtime.h>
#include <math.h>

#define DEV __device__ __forceinline__

typedef _Float16 f16x8 __attribute__((ext_vector_type(8)));
typedef _Float16 f16x4 __attribute__((ext_vector_type(4)));
typedef float    f32x4 __attribute__((ext_vector_type(4)));

DEV float sigmoidf_(float x){ return 1.0f/(1.0f + expf(-x)); }

DEV float wred64(float x){
    #pragma unroll
    for (int off=32; off; off>>=1) x += __shfl_xor(x, off);
    return x;
}

#define MFMA16(a,b,c) __builtin_amdgcn_mfma_f32_16x16x32_f16(a,b,c,0,0,0)

// ---------------- pack helper: frag layout, f16 hi/lo ------------------
DEV void packone(const float* __restrict__ src, int N, int NfrTot, int nfOff,
                 _Float16* __restrict__ Dh, _Float16* __restrict__ Dl, int o){
    int j = o&7, l16 = (o>>3)&15, kg = (o>>7)&3;
    int rest = o>>9;
    int nfl = rest % (N>>4), kt = rest / (N>>4);
    int k = kt*32 + kg*8 + j, n = nfl*16 + l16;
    float x = src[(size_t)k*N + n];
    _Float16 h = (_Float16)x;
    size_t d = ((size_t)kt*NfrTot + nfOff + nfl)*512 + kg*128 + l16*8 + j;
    Dh[d] = h; Dl[d] = (_Float16)(x - (float)h);
}

// ---------------- merged prep: faW, Bh/Bl, Wh/Wl, PKfv, PKxv -----------
__global__ __launch_bounds__(256) void k_prep(
    const float* __restrict__ fa_w1, const float* __restrict__ fa_w2, float* __restrict__ faW,
    const float* __restrict__ fv_w1, const float* __restrict__ fv_w2,
    const float* __restrict__ av_vw, _Float16* __restrict__ Bh, _Float16* __restrict__ Bl,
    const float* __restrict__ v2w, _Float16* __restrict__ Wh, _Float16* __restrict__ Wl,
    const float* __restrict__ lv_wih,
    _Float16* __restrict__ PKfv_h, _Float16* __restrict__ PKfv_l,
    _Float16* __restrict__ PKxv_h, _Float16* __restrict__ PKxv_l)
{
    int bid = blockIdx.x, t = threadIdx.x;
    if (bid < 64){
        int idx = bid*256+t; int m = idx>>7, n = idx&127;
        float acc=0.f;
        for (int k=0;k<256;k++) acc += fa_w1[m*256+k]*fa_w2[k*128+n];
        faW[idx]=acc;
    } else if (bid < 1088){
        int o = (bid-64)*256+t;
        int j = o & 7, l16 = (o>>3)&15, kg = (o>>7)&3, nf = (o>>9)&31, kt = o>>14;
        int k = kt*32 + kg*8 + j, n = nf*16 + l16;
        float x = av_vw[(size_t)k*512 + n];
        _Float16 h = (_Float16)x;
        Bh[o] = h; Bl[o] = (_Float16)(x - (float)h);
    } else if (bid < 1216){
        int o = (bid-1088)*256+t;
        int j = o & 7, l16 = (o>>3)&15, kg = (o>>7)&3, qf = (o>>9)&3, kbg = o>>11;
        int k = kbg*32 + kg*8 + j, q = qf*16 + l16;
        float x = (q < 49) ? v2w[(size_t)k*49 + q] : 0.f;
        _Float16 h = (_Float16)x;
        Wh[o] = h; Wl[o] = (_Float16)(x - (float)h);
    } else if (bid < 1472){
        int o = (bid-1216)*256+t;
        int j=o&7, l16=(o>>3)&15, kg=(o>>7)&3; int rest=o>>9;
        int nfl = rest&7, kt = rest>>3;
        int k = kt*32+kg*8+j, n = nfl*16+l16;
        float acc=0.f;
        for (int kk=0;kk<256;kk++) acc += fv_w1[k*256+kk]*fv_w2[kk*128+n];
        _Float16 h=(_Float16)acc;
        size_t d = ((size_t)kt*8 + nfl)*512 + kg*128 + l16*8 + j;
        PKfv_h[d]=h; PKfv_l[d]=(_Float16)(acc-(float)h);
    } else {
        int seg = (bid-1472)>>8;
        int o = ((bid-1472)&255)*256+t;
        packone(lv_wih + (size_t)seg*65536, 512, 64, seg*32, PKxv_h, PKxv_l, o);
    }
}

// ---------------- fused fa + a_h + ga + xpA, 8 bt, 512 threads ---------
__global__ __launch_bounds__(512) void k_faga2(
    const float* __restrict__ audio, const float* __restrict__ faW,
    const float* __restrict__ av_aw, const float* __restrict__ av_ab,
    const float* __restrict__ av_gw,
    const float* __restrict__ la_wih, const float* __restrict__ la_b,
    float* __restrict__ gGA, float* __restrict__ xpA)
{
    int b0 = blockIdx.x*8; int tid = threadIdx.x;
    __shared__ float sau[8][128], sfa[8][128], sah[8][512];
    for (int i=tid;i<1024;i+=512){ int bt=i>>7,k=i&127; sau[bt][k]=audio[(size_t)(b0+bt)*128+k]; }
    __syncthreads();
    for (int u=0;u<2;u++){
        int i=tid+u*512, bt=i>>7, n=i&127;
        float acc=0.f;
        for (int k4=0;k4<32;k4++){
            float4 x4=*(const float4*)&sau[bt][k4*4];
            acc+=x4.x*faW[(k4*4)*128+n]+x4.y*faW[(k4*4+1)*128+n]
                +x4.z*faW[(k4*4+2)*128+n]+x4.w*faW[(k4*4+3)*128+n];
        }
        sfa[bt][n]=acc;
    }
    __syncthreads();
    {
        int n=tid;
        float bv=av_ab[n];
        float acc[8]={bv,bv,bv,bv,bv,bv,bv,bv};
        for (int k4=0;k4<32;k4++){
            float w0=av_aw[(k4*4)*512+n], w1=av_aw[(k4*4+1)*512+n],
                  w2=av_aw[(k4*4+2)*512+n], w3=av_aw[(k4*4+3)*512+n];
            #pragma unroll
            for (int bt=0;bt<8;bt++){
                float4 x4=*(const float4*)&sfa[bt][k4*4];
                acc[bt]+=x4.x*w0+x4.y*w1+x4.z*w2+x4.w*w3;
            }
        }
        #pragma unroll
        for (int bt=0;bt<8;bt++) sah[bt][n]=fmaxf(acc[bt],0.f);
    }
    __syncthreads();
    if (tid<392){
        int bt=tid/49, q=tid%49;
        float acc=0.f;
        for (int k=0;k<512;k++) acc+=sah[bt][k]*av_gw[k*49+q];
        gGA[(size_t)(b0+bt)*49+q]=acc;
    }
    for (int u=0;u<2;u++){
        int n = tid + u*512;
        int dir = n >> 9, g = n & 511;
        const float* W = la_wih + (size_t)dir*65536;
        float bvv = la_b[dir*512 + g];
        float acc[8] = {bvv,bvv,bvv,bvv,bvv,bvv,bvv,bvv};
        for (int k4=0;k4<32;k4++){
            float w0=W[(k4*4+0)*512+g], w1=W[(k4*4+1)*512+g],
                  w2=W[(k4*4+2)*512+g], w3=W[(k4*4+3)*512+g];
            #pragma unroll
            for (int bt=0;bt<8;bt++){
                float4 x4=*(const float4*)&sfa[bt][k4*4];
                acc[bt]+=x4.x*w0+x4.y*w1+x4.z*w2+x4.w*w3;
            }
        }
        #pragma unroll
        for (int bt=0;bt<8;bt++)
            xpA[((size_t)(b0+bt))*1024 + n] = acc[bt];
    }
}

// ---------------- fully fused AVGA: proven round-7 structure -----------
DEV void cvt4_(float4 v, f16x4& hv, f16x4& lv){
    hv[0]=(_Float16)v.x; lv[0]=(_Float16)(v.x-(float)hv[0]);
    hv[1]=(_Float16)v.y; lv[1]=(_Float16)(v.y-(float)hv[1]);
    hv[2]=(_Float16)v.z; lv[2]=(_Float16)(v.z-(float)hv[2]);
    hv[3]=(_Float16)v.w; lv[3]=(_Float16)(v.w-(float)hv[3]);
}

__global__ __launch_bounds__(256,2) void k_avga_fused(
    const float* __restrict__ video,
    const _Float16* __restrict__ Bh, const _Float16* __restrict__ Bl,
    const float* __restrict__ bias,
    const _Float16* __restrict__ Wh, const _Float16* __restrict__ Wl,
    const float* __restrict__ gGA, const float* __restrict__ hw,
    float* __restrict__ vT)
{
    __shared__ __align__(16) char smem[67072];
    int bt = blockIdx.x;
    int t = threadIdx.x;
    int lane = t & 63, w = t >> 6;
    int l16 = lane & 15, lq = lane >> 4;
    int lb = lane * 16;

    int am = t >> 3, ak = (t & 7) * 4;
    int aoff1 = ((am>>4)*4 + (ak>>3))*256 + (am&15)*16 + (ak&7)*2;
    int am2 = am + 32;
    int aoff2 = ((am2>>4)*4 + (ak>>3))*256 + (am2&15)*16 + (ak&7)*2;
    size_t r1 = (size_t)bt*49 + am;  if (r1 > 125439) r1 = 125439;
    size_t r2 = (size_t)bt*49 + am2; if (r2 > 125439) r2 = 125439;
    const float* Arow1 = video + r1*512 + ak;
    const float* Arow2 = video + r2*512 + ak;

    const f32x4 vzero = {0.f,0.f,0.f,0.f};
    f32x4 acc[4][8];
    #pragma unroll
    for (int p=0;p<4;p++)
        #pragma unroll
        for (int q=0;q<8;q++) acc[p][q] = vzero;

    float4 pa0, pa1;
    pa0 = *(const float4*)(Arow1);
    pa1 = *(const float4*)(Arow2);
    {
        f16x4 hv, lv;
        char* h = &smem[0];
        cvt4_(pa0, hv, lv);
        *(f16x4*)(h + aoff1) = hv; *(f16x4*)(h + 4096 + aoff1) = lv;
        cvt4_(pa1, hv, lv);
        *(f16x4*)(h + aoff2) = hv; *(f16x4*)(h + 4096 + aoff2) = lv;
    }
    __syncthreads();

    for (int kt = 0; kt < 16; ++kt){
        int cur = kt & 1;
        bool more = (kt < 15);
        if (more){
            pa0 = *(const float4*)(Arow1 + (kt+1)*32);
            pa1 = *(const float4*)(Arow2 + (kt+1)*32);
        }
        const char* aB = &smem[cur*8192];
        f16x8 ah[4], al[4];
        #pragma unroll
        for (int p=0;p<4;p++){
            ah[p] = *(const f16x8*)(aB + p*1024 + lb);
            al[p] = *(const f16x8*)(aB + 4096 + p*1024 + lb);
        }
        #pragma unroll
        for (int q=0;q<8;q++){
            size_t bo = (size_t)kt*16384 + (size_t)(w*8 + q)*512 + lane*8;
            f16x8 bh  = *(const f16x8*)(Bh + bo);
            f16x8 bl2 = *(const f16x8*)(Bl + bo);
            #pragma unroll
            for (int p=0;p<4;p++){
                acc[p][q] = MFMA16(ah[p], bh,  acc[p][q]);
                acc[p][q] = MFMA16(ah[p], bl2, acc[p][q]);
                acc[p][q] = MFMA16(al[p], bh,  acc[p][q]);
            }
        }
        if (more){
            char* h = &smem[(cur^1)*8192];
            f16x4 hv, lv;
            cvt4_(pa0, hv, lv);
            *(f16x4*)(h + aoff1) = hv; *(f16x4*)(h + 4096 + aoff1) = lv;
            cvt4_(pa1, hv, lv);
            *(f16x4*)(h + aoff2) = hv; *(f16x4*)(h + 4096 + aoff2) = lv;
        }
        __syncthreads();
    }

    // ---- epilogue: per-wave VH (bias+relu, f16 hi/lo) + content MFMA --
    float bv[8];
    #pragma unroll
    for (int q=0;q<8;q++) bv[q] = bias[w*128 + q*16 + l16];

    char* vh = &smem[16384 + w*8192];
    f32x4 cacc[4][4];
    #pragma unroll
    for (int p=0;p<4;p++)
        #pragma unroll
        for (int qf=0;qf<4;qf++) cacc[p][qf] = vzero;

    #pragma unroll
    for (int c=0;c<4;c++){
        #pragma unroll
        for (int p=0;p<4;p++)
            #pragma unroll
            for (int qq=0;qq<2;qq++){
                int q = c*2 + qq;
                int offbase = p*1024 + (qq*2 + (l16>>3))*256 + (l16&7)*2;
                #pragma unroll
                for (int r=0;r<4;r++){
                    float x = fmaxf(acc[p][q][r] + bv[q], 0.f);
                    _Float16 hh = (_Float16)x;
                    _Float16 ll = (_Float16)(x - (float)hh);
                    int off = offbase + (lq*4 + r)*16;
                    *(_Float16*)(vh + off)        = hh;
                    *(_Float16*)(vh + 4096 + off) = ll;
                }
            }
        int kbg = w*4 + c;
        f16x8 vhh[4], vhl[4];
        #pragma unroll
        for (int p=0;p<4;p++){
            vhh[p] = *(const f16x8*)(vh + p*1024 + lb);
            vhl[p] = *(const f16x8*)(vh + 4096 + p*1024 + lb);
        }
        #pragma unroll
        for (int qf=0;qf<4;qf++){
            size_t wo = (size_t)kbg*2048 + qf*512 + lane*8;
            f16x8 wh = *(const f16x8*)(Wh + wo);
            f16x8 wl = *(const f16x8*)(Wl + wo);
            #pragma unroll
            for (int p=0;p<4;p++){
                cacc[p][qf] = MFMA16(vhh[p], wh, cacc[p][qf]);
                cacc[p][qf] = MFMA16(vhh[p], wl, cacc[p][qf]);
                cacc[p][qf] = MFMA16(vhl[p], wh, cacc[p][qf]);
            }
        }
    }

    // ---- cross-wave content reduce (4-buffer parallel) ----
    __syncthreads();
    float* pw = (float*)&smem[w*16384];
    #pragma unroll
    for (int p=0;p<4;p++)
        #pragma unroll
        for (int qf=0;qf<4;qf++)
            #pragma unroll
            for (int r=0;r<4;r++)
                pw[(p*16 + lq*4 + r)*64 + qf*16 + l16] = cacc[p][qf][r];
    __syncthreads();
    float* cb = (float*)&smem[0];
    for (int i=t; i<4096; i+=256)
        cb[i] = cb[i] + cb[4096+i] + cb[8192+i] + cb[12288+i];
    __syncthreads();

    // ---- z, softmax, weighted sum ----
    float* szp    = (float*)&smem[65536];
    float* salpha = (float*)&smem[66560];
    if (t < 196){
        int p = t >> 2, ds = t & 3;
        float ga = gGA[(size_t)bt*49 + p];
        float part = 0.f;
        for (int q = ds*13; q < ds*13+13 && q < 49; q++)
            part += tanhf(cb[p*64 + q] + ga) * hw[q];
        szp[t] = part;
    }
    __syncthreads();
    if (t < 64){
        float z = (t<49) ? (szp[t*4]+szp[t*4+1]+szp[t*4+2]+szp[t*4+3]) : -1e30f;
        float m = z;
        #pragma unroll
        for (int off=32; off; off>>=1) m = fmaxf(m, __shfl_xor(m, off));
        float e = (t<49)? expf(z - m) : 0.f;
        float s = e;
        #pragma unroll
        for (int off=32; off; off>>=1) s += __shfl_xor(s, off);
        salpha[t] = e / s;
    }
    __syncthreads();
    const float* vb = video + (size_t)bt*49*512;
    #pragma unroll
    for (int u=0;u<2;u++){
        int d = t + u*256;
        float a0 = 0.f;
        for (int p=0;p<49;p++) a0 += salpha[p] * vb[(size_t)p*512 + d];
        vT[(size_t)bt*512 + d] = a0;
    }
}

// ---------------- fused vfea + xpV GEMM (two-phase, MFMA) --------------
__global__ __launch_bounds__(256) void k_gemm2(
    const float* __restrict__ vT,
    const _Float16* __restrict__ Fh, const _Float16* __restrict__ Fl,
    const _Float16* __restrict__ Xh, const _Float16* __restrict__ Xl,
    const float* __restrict__ lv_b,
    float* __restrict__ xpV)
{
    __shared__ __align__(16) char sA[2][4096];
    __shared__ float sV[32][132];
    int t = threadIdx.x, lane = t&63, w = t>>6;
    int l16 = lane&15, lq = lane>>4, lb = lane*16;
    int row0 = blockIdx.x * 32;

    int am = t>>3, ak = (t&7)*4;
    int aoff = ((am>>4)*4 + (ak>>3))*256 + (am&15)*16 + (ak&7)*2;
    const float* Arow = vT + (size_t)(row0+am)*512 + ak;

    const f32x4 vzero = {0.f,0.f,0.f,0.f};
    f32x4 acc1[2][2];
    #pragma unroll
    for (int p=0;p<2;p++)
        #pragma unroll
        for (int q=0;q<2;q++) acc1[p][q] = vzero;

    float4 pa = *(const float4*)(Arow);
    {
        f16x4 hv, lv;
        char* h = &sA[0][0];
        cvt4_(pa, hv, lv);
        *(f16x4*)(h + aoff) = hv; *(f16x4*)(h + 2048 + aoff) = lv;
    }
    __syncthreads();
    for (int kt = 0; kt < 16; ++kt){
        int cur = kt & 1;
        bool more = (kt < 15);
        if (more) pa = *(const float4*)(Arow + (kt+1)*32);
        const char* aB = &sA[cur][0];
        f16x8 ah[2], al[2];
        #pragma unroll
        for (int p=0;p<2;p++){
            ah[p] = *(const f16x8*)(aB + p*1024 + lb);
            al[p] = *(const f16x8*)(aB + 2048 + p*1024 + lb);
        }
        #pragma unroll
        for (int q=0;q<2;q++){
            size_t bo = ((size_t)kt*8 + w*2 + q)*512 + lane*8;
            f16x8 bh  = *(const f16x8*)(Fh + bo);
            f16x8 bl2 = *(const f16x8*)(Fl + bo);
            #pragma unroll
            for (int p=0;p<2;p++){
                acc1[p][q] = MFMA16(ah[p], bh,  acc1[p][q]);
                acc1[p][q] = MFMA16(ah[p], bl2, acc1[p][q]);
                acc1[p][q] = MFMA16(al[p], bh,  acc1[p][q]);
            }
        }
        if (more){
            char* h = &sA[cur^1][0];
            f16x4 hv, lv;
            cvt4_(pa, hv, lv);
            *(f16x4*)(h + aoff) = hv; *(f16x4*)(h + 2048 + aoff) = lv;
        }
        __syncthreads();
    }
    #pragma unroll
    for (int q=0;q<2;q++){
        int n = (w*2+q)*16 + l16;
        #pragma unroll
        for (int p=0;p<2;p++)
            #pragma unroll
            for (int r=0;r<4;r++)
                sV[p*16 + lq*4 + r][n] = acc1[p][q][r];
    }
    __syncthreads();

    int nf0 = blockIdx.y*16 + w*4;
    f32x4 acc2[2][4];
    #pragma unroll
    for (int p=0;p<2;p++)
        #pragma unroll
        for (int q=0;q<4;q++) acc2[p][q] = vzero;

    pa = *(const float4*)&sV[am][ak];
    {
        f16x4 hv, lv;
        char* h = &sA[0][0];
        cvt4_(pa, hv, lv);
        *(f16x4*)(h + aoff) = hv; *(f16x4*)(h + 2048 + aoff) = lv;
    }
    __syncthreads();
    for (int kt = 0; kt < 4; ++kt){
        int cur = kt & 1;
        bool more = (kt < 3);
        if (more) pa = *(const float4*)&sV[am][(kt+1)*32 + ak];
        const char* aB = &sA[cur][0];
        f16x8 ah[2], al[2];
        #pragma unroll
        for (int p=0;p<2;p++){
            ah[p] = *(const f16x8*)(aB + p*1024 + lb);
            al[p] = *(const f16x8*)(aB + 2048 + p*1024 + lb);
        }
        #pragma unroll
        for (int q=0;q<4;q++){
            size_t bo = ((size_t)kt*64 + nf0 + q)*512 + lane*8;
            f16x8 bh  = *(const f16x8*)(Xh + bo);
            f16x8 bl2 = *(const f16x8*)(Xl + bo);
            #pragma unroll
            for (int p=0;p<2;p++){
                acc2[p][q] = MFMA16(ah[p], bh,  acc2[p][q]);
                acc2[p][q] = MFMA16(ah[p], bl2, acc2[p][q]);
                acc2[p][q] = MFMA16(al[p], bh,  acc2[p][q]);
            }
        }
        if (more){
            char* h = &sA[cur^1][0];
            f16x4 hv, lv;
            cvt4_(pa, hv, lv);
            *(f16x4*)(h + aoff) = hv; *(f16x4*)(h + 2048 + aoff) = lv;
        }
        __syncthreads();
    }
    #pragma unroll
    for (int q=0;q<4;q++){
        int n = (nf0+q)*16 + l16;
        float bv = lv_b[n];
        #pragma unroll
        for (int p=0;p<2;p++){
            #pragma unroll
            for (int r=0;r<4;r++)
                xpV[(size_t)(row0 + p*16 + lq*4 + r)*1024 + n] = acc2[p][q][r] + bv;
        }
    }
}

// ---------------- persistent bidirectional LSTMs (512 thr, k-split) ----
__global__ __launch_bounds__(512) void k_lstm(
    const float* __restrict__ xpA, const float* __restrict__ xpV,
    const float* __restrict__ la_whh, const float* __restrict__ lv_whh,
    float* __restrict__ lstm_a, float* __restrict__ lstm_v)
{
    int blk = blockIdx.x;          // 256 blocks
    int c = blk >> 6;
    int chunk = blk & 63;
    int tid = threadIdx.x;
    int j  = tid & 127;
    int bh = (tid >> 7) & 1;
    int kh = tid >> 8;             // k-half 0/1
    const float* whh = ((c<2)? la_whh : lv_whh) + (size_t)(c&1)*65536;
    const float* xpm = (c<2)? xpA : xpV;
    float* outp = (c<2)? lstm_a : lstm_v;
    int dir = c & 1;

    __shared__ float hbuf[4][128];
    __shared__ float pg[4][4][128];
    float cc[2] = {0.f,0.f};
    if (tid < 512) { if (tid < 512 && tid < 512) {} }
    for (int i=tid;i<512;i+=512) ((float*)hbuf)[i] = 0.f;
    __syncthreads();

    for (int s=0; s<10; s++){
        int tt = dir ? (9-s) : s;
        float gi[2]={0.f,0.f}, gf[2]={0.f,0.f}, gg[2]={0.f,0.f}, go[2]={0.f,0.f};
        int k0 = kh*64;
        #pragma unroll 4
        for (int k=k0;k<k0+64;k++){
            float wi = whh[k*512 + j];
            float wf = whh[k*512 + 128 + j];
            float wg = whh[k*512 + 256 + j];
            float wo = whh[k*512 + 384 + j];
            #pragma unroll
            for (int b=0;b<2;b++){
                float hk = hbuf[bh*2+b][k];
                gi[b] += hk*wi; gf[b] += hk*wf; gg[b] += hk*wg; go[b] += hk*wo;
            }
        }
        if (kh==1){
            #pragma unroll
            for (int b=0;b<2;b++){
                int sp = bh*2+b;
                pg[sp][0][j]=gi[b]; pg[sp][1][j]=gf[b];
                pg[sp][2][j]=gg[b]; pg[sp][3][j]=go[b];
            }
        }
        __syncthreads();
        if (kh==0){
            #pragma unroll
            for (int b=0;b<2;b++){
                int gb = chunk*4 + bh*2 + b;
                int sp = bh*2+b;
                const float* xrow = xpm + ((size_t)gb*10 + tt)*1024 + dir*512;
                float gi_ = xrow[j]       + gi[b] + pg[sp][0][j];
                float gf_ = xrow[128+j]   + gf[b] + pg[sp][1][j];
                float gg_ = xrow[256+j]   + gg[b] + pg[sp][2][j];
                float go_ = xrow[384+j]   + go[b] + pg[sp][3][j];
                float i_ = sigmoidf_(gi_);
                float f_ = sigmoidf_(gf_);
                float g_ = tanhf(gg_);
                float o_ = sigmoidf_(go_);
                cc[b] = f_*cc[b] + i_*g_;
                float h_ = o_*tanhf(cc[b]);
                hbuf[sp][j] = h_;
                outp[((size_t)gb*10 + tt)*256 + dir*128 + j] = h_;
            }
        }
        __syncthreads();
    }
}

// ---------------- per-sample tail (512 threads, row-split halves) ------
__global__ __launch_bounds__(512) void k_tail(
    const float* __restrict__ lstm_a, const float* __restrict__ lstm_v,
    const float* __restrict__ vL1, const float* __restrict__ vL2,
    const float* __restrict__ aL1, const float* __restrict__ aL2,
    const float* __restrict__ vfc, const float* __restrict__ afc,
    const float* __restrict__ thrp,
    const float* __restrict__ ln_g, const float* __restrict__ ln_b,
    const float* __restrict__ L1w, const float* __restrict__ L2w,
    float* __restrict__ dout)
{
    int b = blockIdx.x, tid = threadIdx.x;
    int t = tid & 255;
    int half = tid >> 8;
    int lane = tid & 63, w = tid >> 6;
    int wl = w & 3;
    int r0 = half*5;

    __shared__ float sla[10][256], slv[10][256];
    __shared__ float sb1v[10][256], sb2v[10][256], sb1a[10][256], sb2a[10][256];
    __shared__ float sfu[10][256];
    __shared__ float s64[10][64];
    __shared__ float satt[100], s_v2a[100], s_a2v[100];
    __shared__ float sredp[10][4][4];
    __shared__ float scos[10][3][4];

    size_t base = (size_t)b*2560;
    for (int i=tid;i<2560;i+=512){
        ((float*)sla)[i] = lstm_a[base+i];
        ((float*)slv)[i] = lstm_v[base+i];
    }
    __syncthreads();

    {
        float a1[5], a2[5];
        #pragma unroll
        for (int r=0;r<5;r++){ a1[r]=0.f; a2[r]=0.f; }
        #pragma unroll 4
        for (int k=0;k<256;k++){
            float w1 = vL1[k*256+t], w2 = vL2[k*256+t];
            #pragma unroll
            for (int r=0;r<5;r++){ float x=slv[r0+r][k]; a1[r]+=x*w1; a2[r]+=x*w2; }
        }
        #pragma unroll
        for (int r=0;r<5;r++){ sb1v[r0+r][t]=fmaxf(a1[r],0.f); sb2v[r0+r][t]=fmaxf(a2[r],0.f); }
        #pragma unroll
        for (int r=0;r<5;r++){ a1[r]=0.f; a2[r]=0.f; }
        #pragma unroll 4
        for (int k=0;k<256;k++){
            float w1 = aL1[k*256+t], w2 = aL2[k*256+t];
            #pragma unroll
            for (int r=0;r<5;r++){ float x=sla[r0+r][k]; a1[r]+=x*w1; a2[r]+=x*w2; }
        }
        #pragma unroll
        for (int r=0;r<5;r++){ sb1a[r0+r][t]=fmaxf(a1[r],0.f); sb2a[r0+r][t]=fmaxf(a2[r],0.f); }
    }
    __syncthreads();

    if (tid < 100){
        int v = tid/10, a = tid - v*10;
        float acc=0.f;
        for (int k=0;k<256;k++) acc += sb2v[v][k]*sb1a[a][k];
        satt[tid] = fmaxf(acc*(1.0f/16.0f), 0.f);
    }
    __syncthreads();
    float thr = thrp[0];
    if (tid < 10){
        int v = tid;
        float rs=0.f; for(int a=0;a<10;a++) rs += satt[v*10+a];
        float inv = 1.f/(rs+1e-8f);
        float tmp[10]; float rs2=0.f;
        for(int a=0;a<10;a++){ float x = satt[v*10+a]*inv; x = (x>thr)?x:0.f; tmp[a]=x; rs2+=x; }
        float inv2 = 1.f/(rs2+1e-8f);
        for(int a=0;a<10;a++) s_v2a[v*10+a] = tmp[a]*inv2;
    } else if (tid>=16 && tid<26){
        int a = tid-16;
        float cs=0.f; for(int v=0;v<10;v++) cs += satt[v*10+a];
        float inv = 1.f/(cs+1e-8f);
        float tmp[10]; float cs2=0.f;
        for(int v=0;v<10;v++){ float x = satt[v*10+a]*inv; x=(x>thr)?x:0.f; tmp[v]=x; cs2+=x; }
        float inv2 = 1.f/(cs2+1e-8f);
        for(int v=0;v<10;v++) s_a2v[a*10+v] = tmp[v]*inv2;
    }
    __syncthreads();

    #pragma unroll
    for (int v=0;v<5;v++){
        int row = r0+v;
        float acc = slv[row][t];
        #pragma unroll
        for (int a=0;a<10;a++) acc += s_v2a[row*10+a]*sb2a[a][t];
        slv[row][t] = acc;
    }
    #pragma unroll
    for (int a=0;a<5;a++){
        int row = r0+a;
        float acc = sla[row][t];
        #pragma unroll
        for (int v=0;v<10;v++) acc += s_a2v[row*10+v]*sb1v[v][t];
        sla[row][t] = acc;
    }
    __syncthreads();

    float fv[5], fa2[5];
    #pragma unroll
    for (int r=0;r<5;r++){ fv[r]=0.f; fa2[r]=0.f; }
    #pragma unroll 4
    for (int k=0;k<256;k++){
        float wv = vfc[k*256+t], wa = afc[k*256+t];
        #pragma unroll
        for (int r=0;r<5;r++){ fv[r]+=slv[r0+r][k]*wv; fa2[r]+=sla[r0+r][k]*wa; }
    }
    #pragma unroll
    for (int r=0;r<5;r++){ fv[r]=fmaxf(fv[r],0.f); fa2[r]=fmaxf(fa2[r],0.f); }

    #pragma unroll
    for (int r=0;r<5;r++){
        float s1 = wred64(fv[r]);
        float s2 = wred64(fv[r]*fv[r]);
        float s3 = wred64(fa2[r]);
        float s4 = wred64(fa2[r]*fa2[r]);
        if (lane==0){
            sredp[r0+r][0][wl] = s1; sredp[r0+r][1][wl] = s2;
            sredp[r0+r][2][wl] = s3; sredp[r0+r][3][wl] = s4;
        }
    }
    __syncthreads();
    float gt = ln_g[t], bt2 = ln_b[t];
    #pragma unroll
    for (int r=0;r<5;r++){
        int row = r0+r;
        float s1 = sredp[row][0][0]+sredp[row][0][1]+sredp[row][0][2]+sredp[row][0][3];
        float s2 = sredp[row][1][0]+sredp[row][1][1]+sredp[row][1][2]+sredp[row][1][3];
        float s3 = sredp[row][2][0]+sredp[row][2][1]+sredp[row][2][2]+sredp[row][2][3];
        float s4 = sredp[row][3][0]+sredp[row][3][1]+sredp[row][3][2]+sredp[row][3][3];
        float muv = s1*(1.f/256.f);
        float varv = s2*(1.f/256.f) - muv*muv;
        float rsv = 1.f/sqrtf(varv+1e-6f);
        float vln = (fv[r]-muv)*rsv*gt + bt2;
        float mua = s3*(1.f/256.f);
        float vara = s4*(1.f/256.f) - mua*mua;
        float rsa = 1.f/sqrtf(vara+1e-6f);
        float aln = (fa2[r]-mua)*rsa*gt + bt2;
        float fu = 0.5f*(vln+aln);
        dout[(size_t)(b*10+row)*256 + t] = fu;
        sfu[row][t] = fu;
        float c1 = wred64(vln*vln);
        float c2 = wred64(aln*aln);
        float c3 = wred64(vln*aln);
        if (lane==0){
            scos[row][0][wl] = c1; scos[row][1][wl] = c2; scos[row][2][wl] = c3;
        }
    }
    __syncthreads();
    if (tid < 10){
        int r = tid;
        float nv2 = scos[r][0][0]+scos[r][0][1]+scos[r][0][2]+scos[r][0][3];
        float na2 = scos[r][1][0]+scos[r][1][1]+scos[r][1][2]+scos[r][1][3];
        float dva = scos[r][2][0]+scos[r][2][1]+scos[r][2][2]+scos[r][2][3];
        float nv = fmaxf(sqrtf(nv2), 1e-12f);
        float na = fmaxf(sqrtf(na2), 1e-12f);
        dout[729600 + b*10 + r] = dva/(nv*na);
    }

    #pragma unroll
    for (int pass=0; pass<2; ++pass){
        int r = pass*8 + w;
        if (r < 10){
            float acc = 0.f;
            for (int k4=0;k4<64;k4++){
                float4 f4 = *(const float4*)&sfu[r][k4*4];
                acc += f4.x*L1w[(k4*4)*64+lane] + f4.y*L1w[(k4*4+1)*64+lane]
                     + f4.z*L1w[(k4*4+2)*64+lane] + f4.w*L1w[(k4*4+3)*64+lane];
            }
            s64[r][lane] = fmaxf(acc, 0.f);
        }
    }
    __syncthreads();
    for (int i=tid; i<290; i+=512){
        int r = i/29, jj = i - r*29;
        float acc = 0.f;
        #pragma unroll
        for (int k=0;k<64;k++) acc += s64[r][k]*L2w[k*29+jj];
        dout[655360 + (size_t)(b*10+r)*29 + jj] = acc;
    }
}

// =======================================================================
extern "C" void kernel_launch(void* const* d_in, const int* in_sizes, int n_in,
                              void* d_out, int out_size, void* d_ws, size_t ws_size,
                              hipStream_t stream) {
    const float* audio  = (const float*)d_in[0];
    const float* video  = (const float*)d_in[1];
    const float* thrp   = (const float*)d_in[2];
    const float* fa_w1  = (const float*)d_in[3];
    const float* fa_w2  = (const float*)d_in[4];
    const float* av_aw  = (const float*)d_in[5];
    const float* av_ab  = (const float*)d_in[6];
    const float* av_vw  = (const float*)d_in[7];
    const float* av_vb  = (const float*)d_in[8];
    const float* av_v2w = (const float*)d_in[9];
    const float* av_gw  = (const float*)d_in[10];
    const float* av_hw  = (const float*)d_in[11];
    const float* fv_w1  = (const float*)d_in[12];
    const float* fv_w2  = (const float*)d_in[13];
    const float* la_wih = (const float*)d_in[14];
    const float* la_whh = (const float*)d_in[15];
    const float* la_b   = (const float*)d_in[16];
    const float* lv_wih = (const float*)d_in[17];
    const float* lv_whh = (const float*)d_in[18];
    const float* lv_b   = (const float*)d_in[19];
    const float* vL1    = (const float*)d_in[20];
    const float* vL2    = (const float*)d_in[21];
    const float* aL1    = (const float*)d_in[22];
    const float* aL2    = (const float*)d_in[23];
    const float* vfc    = (const float*)d_in[24];
    const float* afc    = (const float*)d_in[25];
    const float* ln_g   = (const float*)d_in[26];
    const float* ln_b   = (const float*)d_in[27];
    const float* L1w    = (const float*)d_in[28];
    const float* L2w    = (const float*)d_in[29];
    float* dout = (float*)d_out;
    float* ws = (float*)d_ws;

    // workspace layout (float offsets)
    float* faW  = ws;                 // 16384
    float* gGA  = ws + 409600;        // 125440
    float* vT   = ws + 535040;        // 1310720
    float* xpA  = ws + 2173440;       // 2621440
    float* xpV  = ws + 4794880;       // 2621440
    float* la   = ws + 7416320;       // 655360
    float* lv   = ws + 8071680;       // 655360
    _Float16* Bh = (_Float16*)(ws + 12659200);
    _Float16* Bl = (_Float16*)(ws + 12790272);
    _Float16* Wh = (_Float16*)(ws + 12921344);
    _Float16* Wl = (_Float16*)(ws + 12937728);
    _Float16* PKfv_h = (_Float16*)(ws + 12954112);
    _Float16* PKfv_l = (_Float16*)(ws + 12986880);
    _Float16* PKxv_h = (_Float16*)(ws + 13150720);
    _Float16* PKxv_l = (_Float16*)(ws + 13216256);

    k_prep<<<1984, 256, 0, stream>>>(fa_w1, fa_w2, faW, fv_w1, fv_w2,
                                     av_vw, Bh, Bl, av_v2w, Wh, Wl,
                                     lv_wih, PKfv_h, PKfv_l, PKxv_h, PKxv_l);
    k_faga2<<<320, 512, 0, stream>>>(audio, faW, av_aw, av_ab, av_gw,
                                     la_wih, la_b, gGA, xpA);
    k_avga_fused<<<2560, 256, 0, stream>>>(video, Bh, Bl, av_vb, Wh, Wl,
                                           gGA, av_hw, vT);
    k_gemm2<<<dim3(80,4), 256, 0, stream>>>(vT, PKfv_h, PKfv_l,
                                            PKxv_h, PKxv_l, lv_b, xpV);
    k_lstm<<<256, 512, 0, stream>>>(xpA, xpV, la_whh, lv_whh, la, lv);
    k_tail<<<256, 512, 0, stream>>>(la, lv, vL1, vL2, aL1, aL2, vfc, afc,
                                    thrp, ln_g, ln_b, L1w, L2w, dout);
}